// Round 1
// baseline (576.263 us; speedup 1.0000x reference)
//
#include <hip/hip_runtime.h>
#include <hip/hip_bf16.h>
#include <math.h>

#define NN 50000
#define NE 800000

typedef short bf16x8 __attribute__((ext_vector_type(8)));
typedef float f32x4 __attribute__((ext_vector_type(4)));
typedef unsigned short us4 __attribute__((ext_vector_type(4)));

__device__ __forceinline__ float bf2f(unsigned short u) {
  union { unsigned int i; float f; } x; x.i = ((unsigned int)u) << 16; return x.f;
}
__device__ __forceinline__ unsigned short f2bf(float f) {
  union { float f; unsigned int i; } x; x.f = f;
  unsigned int i = x.i;
  unsigned int r = i + 0x7FFF + ((i >> 16) & 1);   // round-to-nearest-even
  return (unsigned short)(r >> 16);
}

// ---------------- CSR build ----------------
__global__ void deg_kernel(const int* __restrict__ dstn, int* __restrict__ deg) {
  int e = blockIdx.x * 256 + threadIdx.x;
  if (e < NE) atomicAdd(&deg[dstn[e]], 1);
}

__global__ void scan1_kernel(const int* __restrict__ deg, int* __restrict__ rowoff,
                             int* __restrict__ partials, int nel, int ndeg) {
  __shared__ int s[256];
  int t = threadIdx.x;
  int i = blockIdx.x * 256 + t;
  int v = (i < ndeg) ? deg[i] : 0;
  s[t] = v; __syncthreads();
  for (int off = 1; off < 256; off <<= 1) {
    int x = (t >= off) ? s[t - off] : 0;
    __syncthreads();
    s[t] += x;
    __syncthreads();
  }
  if (i < nel) rowoff[i] = s[t] - v;     // exclusive
  if (t == 255) partials[blockIdx.x] = s[255];
}

__global__ void scan2_kernel(int* __restrict__ partials, int nparts) {
  __shared__ int s[256];
  int t = threadIdx.x;
  int v = (t < nparts) ? partials[t] : 0;
  s[t] = v; __syncthreads();
  for (int off = 1; off < 256; off <<= 1) {
    int x = (t >= off) ? s[t - off] : 0;
    __syncthreads();
    s[t] += x;
    __syncthreads();
  }
  if (t < nparts) partials[t] = s[t] - v;  // exclusive
}

__global__ void scan3_kernel(int* __restrict__ rowoff, const int* __restrict__ partials, int nel) {
  int i = blockIdx.x * 256 + threadIdx.x;
  if (i < nel) rowoff[i] += partials[blockIdx.x];
}

__global__ void fill_kernel(const int* __restrict__ srcn, const int* __restrict__ dstn,
                            const int* __restrict__ rowoff, int* __restrict__ cursor,
                            int* __restrict__ csr) {
  int e = blockIdx.x * 256 + threadIdx.x;
  if (e >= NE) return;
  int d = dstn[e];
  int pos = atomicAdd(&cursor[d], 1);
  csr[rowoff[d] + pos] = srcn[e];
}

// ---------------- weight prep: f32 [K][N] -> bf16 transposed [N][K] ----------------
__global__ void prep_kernel(const float* w1n, const float* w1r, const float* w2n, const float* w2r,
                            const float* wfn, const float* wfr, const float* wr1, const float* wr2,
                            unsigned short* Bt1, unsigned short* Bt2, unsigned short* Bt3,
                            unsigned short* Br1, unsigned short* Br2) {
  int g = blockIdx.x * 256 + threadIdx.x;
  const float* W; unsigned short* D; int Nseg, dstride, koff;
  if      (g <  16384) {              W = w1n; D = Bt1; Nseg = 128; dstride = 256; koff = 0;   }
  else if (g <  32768) { g -= 16384;  W = w1r; D = Bt1; Nseg = 128; dstride = 256; koff = 128; }
  else if (g <  49152) { g -= 32768;  W = w2n; D = Bt2; Nseg = 128; dstride = 256; koff = 0;   }
  else if (g <  65536) { g -= 49152;  W = w2r; D = Bt2; Nseg = 128; dstride = 256; koff = 128; }
  else if (g <  73728) { g -= 65536;  W = wfn; D = Bt3; Nseg = 64;  dstride = 256; koff = 0;   }
  else if (g <  81920) { g -= 73728;  W = wfr; D = Bt3; Nseg = 64;  dstride = 256; koff = 128; }
  else if (g <  98304) { g -= 81920;  W = wr1; D = Br1; Nseg = 128; dstride = 128; koff = 0;   }
  else if (g < 106496) { g -= 98304;  W = wr2; D = Br2; Nseg = 64;  dstride = 128; koff = 0;   }
  else return;
  int n = g >> 7, k = g & 127;       // all weights have K=128 rows
  D[n * dstride + koff + k] = f2bf(W[k * Nseg + n]);
}

// ---------------- z (f32) -> bf16 into A1 right half ----------------
__global__ void convz_kernel(const float* __restrict__ z, unsigned short* __restrict__ A1) {
  int i = blockIdx.x * 256 + threadIdx.x;   // groups of 4 elements
  if (i >= NN * 128 / 4) return;
  int i4 = i * 4;
  int row = i4 >> 7, c = i4 & 127;
  float4 v = *(const float4*)(z + i4);
  us4 o = { f2bf(v.x), f2bf(v.y), f2bf(v.z), f2bf(v.w) };
  *(us4*)(A1 + (size_t)row * 256 + 128 + c) = o;
}

// ---------------- mean aggregation: one wave per node ----------------
__global__ __launch_bounds__(256) void agg_kernel(const unsigned short* __restrict__ feat, int fstride,
                                                  unsigned short* __restrict__ outm, int ostride,
                                                  const int* __restrict__ rowoff,
                                                  const int* __restrict__ csr) {
  int wave = threadIdx.x >> 6, lane = threadIdx.x & 63;
  int node = blockIdx.x * 4 + wave;
  if (node >= NN) return;
  int beg = rowoff[node], end = rowoff[node + 1];
  float a0 = 0.f, a1 = 0.f;
  for (int j = beg; j < end; ++j) {
    int s = csr[j];
    unsigned int v = *(const unsigned int*)(feat + (size_t)s * fstride + (lane << 1));
    a0 += bf2f((unsigned short)(v & 0xffff));
    a1 += bf2f((unsigned short)(v >> 16));
  }
  float inv = 1.f / fmaxf((float)(end - beg), 1.f);
  unsigned int w = ((unsigned int)f2bf(a1 * inv) << 16) | f2bf(a0 * inv);
  *(unsigned int*)(outm + (size_t)node * ostride + (lane << 1)) = w;
}

// ---------------- bf16 MFMA GEMM, fragments straight from global ----------------
// A [M x K] bf16 row-major (stride a_stride), Bt [N x K] bf16 (stride bt_stride).
// out = opt_sigmoid8( opt_res( opt_relu( A@B + bias ) ) ), written bf16 and/or f32.
__global__ __launch_bounds__(256) void gemm_kernel(
    const unsigned short* __restrict__ A, int a_stride,
    const unsigned short* __restrict__ Bt, int bt_stride,
    const float* __restrict__ bias,
    const float* __restrict__ res, int res_stride,
    unsigned short* __restrict__ out_bf, int obf_stride,
    float* __restrict__ out_f, int of_stride,
    int M, int N, int K, int relu, int sig8)
{
  int wave = threadIdx.x >> 6;
  int lane = threadIdx.x & 63;
  int row0 = blockIdx.x * 64 + wave * 16;
  if (row0 >= M) return;
  int m = lane & 15, q = lane >> 4;
  int ntiles = N >> 4;
  f32x4 acc[8];
#pragma unroll
  for (int i = 0; i < 8; i++) acc[i] = (f32x4){0.f, 0.f, 0.f, 0.f};
  const unsigned short* arow = A + (size_t)(row0 + m) * a_stride + q * 8;
  for (int k0 = 0; k0 < K; k0 += 32) {
    bf16x8 af = *(const bf16x8*)(arow + k0);
    const unsigned short* brow = Bt + (size_t)m * bt_stride + k0 + q * 8;
    for (int nt = 0; nt < ntiles; ++nt) {
      bf16x8 bfr = *(const bf16x8*)(brow + (size_t)nt * 16 * bt_stride);
      acc[nt] = __builtin_amdgcn_mfma_f32_16x16x32_bf16(af, bfr, acc[nt], 0, 0, 0);
    }
  }
  int orow0 = row0 + q * 4;
  for (int nt = 0; nt < ntiles; ++nt) {
    int col = nt * 16 + m;
    float bb = bias[col];
#pragma unroll
    for (int r = 0; r < 4; r++) {
      float v = acc[nt][r] + bb;
      if (relu) v = fmaxf(v, 0.f);
      if (res)  v += res[(size_t)(orow0 + r) * res_stride + col];
      if (sig8 && col < 8) v = 1.f / (1.f + __expf(-v));
      if (out_bf) out_bf[(size_t)(orow0 + r) * obf_stride + col] = f2bf(v);
      if (out_f)  out_f[(size_t)(orow0 + r) * of_stride + col] = v;
    }
  }
}

extern "C" void kernel_launch(void* const* d_in, const int* in_sizes, int n_in,
                              void* d_out, int out_size, void* d_ws, size_t ws_size,
                              hipStream_t stream) {
  const float* z   = (const float*)d_in[0];
  const int*   edge = (const int*)d_in[1];
  const int*   srcn = edge;        // edge_index[0]
  const int*   dstn = edge + NE;   // edge_index[1]
  const float* w1n = (const float*)d_in[2];
  const float* w1r = (const float*)d_in[3];
  const float* b1  = (const float*)d_in[4];
  const float* w2n = (const float*)d_in[5];
  const float* w2r = (const float*)d_in[6];
  const float* b2  = (const float*)d_in[7];
  const float* wfn = (const float*)d_in[8];
  const float* wfr = (const float*)d_in[9];
  const float* bfb = (const float*)d_in[10];
  const float* wr1 = (const float*)d_in[11];
  const float* br1 = (const float*)d_in[12];
  const float* wr2 = (const float*)d_in[13];
  const float* br2 = (const float*)d_in[14];
  float* out = (float*)d_out;

  char* p = (char*)d_ws;
  auto alloc = [&](size_t bytes) { char* r = p; p += (bytes + 255) & ~255ull; return r; };
  int* deg    = (int*)alloc((size_t)NN * 4);
  int* cursor = (int*)alloc((size_t)NN * 4);
  int* rowoff = (int*)alloc((size_t)(NN + 1) * 4);
  int* partials = (int*)alloc(256 * 4);
  int* csr    = (int*)alloc((size_t)NE * 4);
  unsigned short* A1 = (unsigned short*)alloc((size_t)NN * 256 * 2);  // [mean1|z_bf], later reused as A3
  unsigned short* A2 = (unsigned short*)alloc((size_t)NN * 256 * 2);  // [mean2|h1]
  float* res1 = (float*)alloc((size_t)NN * 128 * 4);
  float* res2 = (float*)alloc((size_t)NN * 64 * 4);
  unsigned short* Bt1 = (unsigned short*)alloc(128 * 256 * 2);
  unsigned short* Bt2 = (unsigned short*)alloc(128 * 256 * 2);
  unsigned short* Bt3 = (unsigned short*)alloc(64 * 256 * 2);
  unsigned short* Br1 = (unsigned short*)alloc(128 * 128 * 2);
  unsigned short* Br2 = (unsigned short*)alloc(64 * 128 * 2);
  unsigned short* A3 = A1;  // alias: A1 dead once res1/res2 computed and G2 output lands in A3 right half

  // zero deg + cursor (contiguous region)
  size_t zlen = (size_t)((char*)cursor - (char*)deg) + (size_t)NN * 4;
  hipMemsetAsync(deg, 0, zlen, stream);

  // CSR build
  deg_kernel<<<(NE + 255) / 256, 256, 0, stream>>>(dstn, deg);
  int nel = NN + 1;
  int nblk = (nel + 255) / 256;   // 196
  scan1_kernel<<<nblk, 256, 0, stream>>>(deg, rowoff, partials, nel, NN);
  scan2_kernel<<<1, 256, 0, stream>>>(partials, nblk);
  scan3_kernel<<<nblk, 256, 0, stream>>>(rowoff, partials, nel);
  fill_kernel<<<(NE + 255) / 256, 256, 0, stream>>>(srcn, dstn, rowoff, cursor, csr);

  // weight prep + z conversion
  prep_kernel<<<416, 256, 0, stream>>>(w1n, w1r, w2n, w2r, wfn, wfr, wr1, wr2,
                                       Bt1, Bt2, Bt3, Br1, Br2);
  convz_kernel<<<(NN * 128 / 4 + 255) / 256, 256, 0, stream>>>(z, A1);

  const int gemm_blocks = (NN + 63) / 64;  // 782
  const int agg_blocks  = (NN + 3) / 4;    // 12500

  // layer 1: mean1 = agg(z);  h1 = relu([mean1|z]@[w1n;w1r]+b1) -> A2 right half
  agg_kernel<<<agg_blocks, 256, 0, stream>>>(A1 + 128, 256, A1, 256, rowoff, csr);
  gemm_kernel<<<gemm_blocks, 256, 0, stream>>>(A1, 256, Bt1, 256, b1,
      nullptr, 0, A2 + 128, 256, nullptr, 0, NN, 128, 256, 1, 0);

  // residuals from z (A1 right half): res1 = z@wr1+br1 (f32), res2 = z@wr2+br2 (f32)
  gemm_kernel<<<gemm_blocks, 256, 0, stream>>>(A1 + 128, 256, Br1, 128, br1,
      nullptr, 0, nullptr, 0, res1, 128, NN, 128, 128, 0, 0);
  gemm_kernel<<<gemm_blocks, 256, 0, stream>>>(A1 + 128, 256, Br2, 128, br2,
      nullptr, 0, nullptr, 0, res2, 64, NN, 64, 128, 0, 0);

  // layer 2: mean2 = agg(h1);  h2 = relu([mean2|h1]@[w2n;w2r]+b2) + res1 -> A3 right half
  agg_kernel<<<agg_blocks, 256, 0, stream>>>(A2 + 128, 256, A2, 256, rowoff, csr);
  gemm_kernel<<<gemm_blocks, 256, 0, stream>>>(A2, 256, Bt2, 256, b2,
      res1, 128, A3 + 128, 256, nullptr, 0, NN, 128, 256, 1, 0);

  // layer 3: mean3 = agg(h2);  out = [mean3|h2]@[wfn;wfr]+bf + res2, sigmoid on cols 0..7
  agg_kernel<<<agg_blocks, 256, 0, stream>>>(A3 + 128, 256, A3, 256, rowoff, csr);
  gemm_kernel<<<gemm_blocks, 256, 0, stream>>>(A3, 256, Bt3, 256, bfb,
      res2, 64, nullptr, 0, out, 64, NN, 64, 256, 0, 1);
}

// Round 2
// 432.605 us; speedup vs baseline: 1.3321x; 1.3321x over previous
//
#include <hip/hip_runtime.h>
#include <hip/hip_bf16.h>
#include <math.h>

#define NN 50000
#define NE 800000

typedef short bf16x8 __attribute__((ext_vector_type(8)));
typedef float f32x4 __attribute__((ext_vector_type(4)));
typedef unsigned short us4 __attribute__((ext_vector_type(4)));
typedef unsigned int u32x4 __attribute__((ext_vector_type(4)));

__device__ __forceinline__ float bf2f(unsigned short u) {
  union { unsigned int i; float f; } x; x.i = ((unsigned int)u) << 16; return x.f;
}
__device__ __forceinline__ unsigned short f2bf(float f) {
  union { float f; unsigned int i; } x; x.f = f;
  unsigned int i = x.i;
  unsigned int r = i + 0x7FFF + ((i >> 16) & 1);   // round-to-nearest-even
  return (unsigned short)(r >> 16);
}

// ---------------- CSR build ----------------
__global__ void deg_kernel(const int* __restrict__ dstn, int* __restrict__ deg) {
  int e = blockIdx.x * 256 + threadIdx.x;
  if (e < NE) atomicAdd(&deg[dstn[e]], 1);
}

__global__ void scan1_kernel(const int* __restrict__ deg, int* __restrict__ rowoff,
                             int* __restrict__ partials, int nel, int ndeg) {
  __shared__ int s[256];
  int t = threadIdx.x;
  int i = blockIdx.x * 256 + t;
  int v = (i < ndeg) ? deg[i] : 0;
  s[t] = v; __syncthreads();
  for (int off = 1; off < 256; off <<= 1) {
    int x = (t >= off) ? s[t - off] : 0;
    __syncthreads();
    s[t] += x;
    __syncthreads();
  }
  if (i < nel) rowoff[i] = s[t] - v;     // exclusive
  if (t == 255) partials[blockIdx.x] = s[255];
}

__global__ void scan2_kernel(int* __restrict__ partials, int nparts) {
  __shared__ int s[256];
  int t = threadIdx.x;
  int v = (t < nparts) ? partials[t] : 0;
  s[t] = v; __syncthreads();
  for (int off = 1; off < 256; off <<= 1) {
    int x = (t >= off) ? s[t - off] : 0;
    __syncthreads();
    s[t] += x;
    __syncthreads();
  }
  if (t < nparts) partials[t] = s[t] - v;  // exclusive
}

__global__ void scan3_kernel(int* __restrict__ rowoff, const int* __restrict__ partials, int nel) {
  int i = blockIdx.x * 256 + threadIdx.x;
  if (i < nel) rowoff[i] += partials[blockIdx.x];
}

__global__ void fill_kernel(const int* __restrict__ srcn, const int* __restrict__ dstn,
                            const int* __restrict__ rowoff, int* __restrict__ cursor,
                            int* __restrict__ csr) {
  int e = blockIdx.x * 256 + threadIdx.x;
  if (e >= NE) return;
  int d = dstn[e];
  int pos = atomicAdd(&cursor[d], 1);
  csr[rowoff[d] + pos] = srcn[e];
}

// ---------------- weight prep: f32 [K][N] -> bf16 transposed [N][K] ----------------
__global__ void prep_kernel(const float* w1n, const float* w1r, const float* w2n, const float* w2r,
                            const float* wfn, const float* wfr, const float* wr1, const float* wr2,
                            unsigned short* Bt1, unsigned short* Bt2, unsigned short* Bt3,
                            unsigned short* Br1, unsigned short* Br2) {
  int g = blockIdx.x * 256 + threadIdx.x;
  const float* W; unsigned short* D; int Nseg, dstride, koff;
  if      (g <  16384) {              W = w1n; D = Bt1; Nseg = 128; dstride = 256; koff = 0;   }
  else if (g <  32768) { g -= 16384;  W = w1r; D = Bt1; Nseg = 128; dstride = 256; koff = 128; }
  else if (g <  49152) { g -= 32768;  W = w2n; D = Bt2; Nseg = 128; dstride = 256; koff = 0;   }
  else if (g <  65536) { g -= 49152;  W = w2r; D = Bt2; Nseg = 128; dstride = 256; koff = 128; }
  else if (g <  73728) { g -= 65536;  W = wfn; D = Bt3; Nseg = 64;  dstride = 256; koff = 0;   }
  else if (g <  81920) { g -= 73728;  W = wfr; D = Bt3; Nseg = 64;  dstride = 256; koff = 128; }
  else if (g <  98304) { g -= 81920;  W = wr1; D = Br1; Nseg = 128; dstride = 128; koff = 0;   }
  else if (g < 106496) { g -= 98304;  W = wr2; D = Br2; Nseg = 64;  dstride = 128; koff = 0;   }
  else return;
  int n = g >> 7, k = g & 127;       // all weights have K=128 rows
  D[n * dstride + koff + k] = f2bf(W[k * Nseg + n]);
}

// ---------------- z (f32) -> bf16 into A1 right half ----------------
__global__ void convz_kernel(const float* __restrict__ z, unsigned short* __restrict__ A1) {
  int i = blockIdx.x * 256 + threadIdx.x;   // groups of 4 elements
  if (i >= NN * 128 / 4) return;
  int i4 = i * 4;
  int row = i4 >> 7, c = i4 & 127;
  float4 v = *(const float4*)(z + i4);
  us4 o = { f2bf(v.x), f2bf(v.y), f2bf(v.z), f2bf(v.w) };
  *(us4*)(A1 + (size_t)row * 256 + 128 + c) = o;
}

// ---------------- mean aggregation: one wave per node, 4 neighbors in flight ----
// Wave split into 4 subgroups of 16 lanes; subgroup g handles neighbors beg+g,
// beg+g+4, ... with 16B/lane loads (16 lanes x 16B = one 256B feature row).
// Unroll x2 -> up to 8 independent row-reads outstanding per wave.
__global__ __launch_bounds__(256) void agg_kernel(const unsigned short* __restrict__ feat, int fstride,
                                                  unsigned short* __restrict__ outm, int ostride,
                                                  const int* __restrict__ rowoff,
                                                  const int* __restrict__ csr) {
  int wave = threadIdx.x >> 6, lane = threadIdx.x & 63;
  int node = blockIdx.x * 4 + wave;
  if (node >= NN) return;
  int beg = rowoff[node], end = rowoff[node + 1];
  int g = lane >> 4;           // neighbor subgroup 0..3
  int c = (lane & 15) << 3;    // column offset (8 bf16 = 16B per lane)
  float a[8];
#pragma unroll
  for (int i = 0; i < 8; i++) a[i] = 0.f;
  int j = beg + g;
  for (; j + 4 < end; j += 8) {
    int s0 = csr[j];
    int s1 = csr[j + 4];
    u32x4 v0 = *(const u32x4*)(feat + (size_t)s0 * fstride + c);
    u32x4 v1 = *(const u32x4*)(feat + (size_t)s1 * fstride + c);
#pragma unroll
    for (int i = 0; i < 4; i++) {
      a[2*i]   += bf2f((unsigned short)(v0[i] & 0xffff));
      a[2*i+1] += bf2f((unsigned short)(v0[i] >> 16));
      a[2*i]   += bf2f((unsigned short)(v1[i] & 0xffff));
      a[2*i+1] += bf2f((unsigned short)(v1[i] >> 16));
    }
  }
  if (j < end) {
    int s0 = csr[j];
    u32x4 v0 = *(const u32x4*)(feat + (size_t)s0 * fstride + c);
#pragma unroll
    for (int i = 0; i < 4; i++) {
      a[2*i]   += bf2f((unsigned short)(v0[i] & 0xffff));
      a[2*i+1] += bf2f((unsigned short)(v0[i] >> 16));
    }
  }
  // reduce the 4 subgroups (lanes differing in bits 4 and 5)
#pragma unroll
  for (int i = 0; i < 8; i++) {
    a[i] += __shfl_xor(a[i], 16, 64);
    a[i] += __shfl_xor(a[i], 32, 64);
  }
  if (g == 0) {
    float inv = 1.f / fmaxf((float)(end - beg), 1.f);
    unsigned int o[4];
#pragma unroll
    for (int i = 0; i < 4; i++)
      o[i] = ((unsigned int)f2bf(a[2*i+1] * inv) << 16) | f2bf(a[2*i] * inv);
    *(u32x4*)(outm + (size_t)node * ostride + c) = *(const u32x4*)o;
  }
}

// ---------------- bf16 MFMA GEMM, fragments straight from global ----------------
// A [M x K] bf16 row-major (stride a_stride), Bt [N x K] bf16 (stride bt_stride).
// out = opt_sigmoid8( opt_res( opt_relu( A@B + bias ) ) ), written bf16 and/or f32.
__global__ __launch_bounds__(256) void gemm_kernel(
    const unsigned short* __restrict__ A, int a_stride,
    const unsigned short* __restrict__ Bt, int bt_stride,
    const float* __restrict__ bias,
    const float* __restrict__ res, int res_stride,
    unsigned short* __restrict__ out_bf, int obf_stride,
    float* __restrict__ out_f, int of_stride,
    int M, int N, int K, int relu, int sig8)
{
  int wave = threadIdx.x >> 6;
  int lane = threadIdx.x & 63;
  int row0 = blockIdx.x * 64 + wave * 16;
  if (row0 >= M) return;
  int m = lane & 15, q = lane >> 4;
  int ntiles = N >> 4;
  f32x4 acc[8];
#pragma unroll
  for (int i = 0; i < 8; i++) acc[i] = (f32x4){0.f, 0.f, 0.f, 0.f};
  const unsigned short* arow = A + (size_t)(row0 + m) * a_stride + q * 8;
  for (int k0 = 0; k0 < K; k0 += 32) {
    bf16x8 af = *(const bf16x8*)(arow + k0);
    const unsigned short* brow = Bt + (size_t)m * bt_stride + k0 + q * 8;
    for (int nt = 0; nt < ntiles; ++nt) {
      bf16x8 bfr = *(const bf16x8*)(brow + (size_t)nt * 16 * bt_stride);
      acc[nt] = __builtin_amdgcn_mfma_f32_16x16x32_bf16(af, bfr, acc[nt], 0, 0, 0);
    }
  }
  int orow0 = row0 + q * 4;
  for (int nt = 0; nt < ntiles; ++nt) {
    int col = nt * 16 + m;
    float bb = bias[col];
#pragma unroll
    for (int r = 0; r < 4; r++) {
      float v = acc[nt][r] + bb;
      if (relu) v = fmaxf(v, 0.f);
      if (res)  v += res[(size_t)(orow0 + r) * res_stride + col];
      if (sig8 && col < 8) v = 1.f / (1.f + __expf(-v));
      if (out_bf) out_bf[(size_t)(orow0 + r) * obf_stride + col] = f2bf(v);
      if (out_f)  out_f[(size_t)(orow0 + r) * of_stride + col] = v;
    }
  }
}

extern "C" void kernel_launch(void* const* d_in, const int* in_sizes, int n_in,
                              void* d_out, int out_size, void* d_ws, size_t ws_size,
                              hipStream_t stream) {
  const float* z   = (const float*)d_in[0];
  const int*   edge = (const int*)d_in[1];
  const int*   srcn = edge;        // edge_index[0]
  const int*   dstn = edge + NE;   // edge_index[1]
  const float* w1n = (const float*)d_in[2];
  const float* w1r = (const float*)d_in[3];
  const float* b1  = (const float*)d_in[4];
  const float* w2n = (const float*)d_in[5];
  const float* w2r = (const float*)d_in[6];
  const float* b2  = (const float*)d_in[7];
  const float* wfn = (const float*)d_in[8];
  const float* wfr = (const float*)d_in[9];
  const float* bfb = (const float*)d_in[10];
  const float* wr1 = (const float*)d_in[11];
  const float* br1 = (const float*)d_in[12];
  const float* wr2 = (const float*)d_in[13];
  const float* br2 = (const float*)d_in[14];
  float* out = (float*)d_out;

  char* p = (char*)d_ws;
  auto alloc = [&](size_t bytes) { char* r = p; p += (bytes + 255) & ~255ull; return r; };
  int* deg    = (int*)alloc((size_t)NN * 4);
  int* cursor = (int*)alloc((size_t)NN * 4);
  int* rowoff = (int*)alloc((size_t)(NN + 1) * 4);
  int* partials = (int*)alloc(256 * 4);
  int* csr    = (int*)alloc((size_t)NE * 4);
  unsigned short* A1 = (unsigned short*)alloc((size_t)NN * 256 * 2);  // [mean1|z_bf], later reused as A3
  unsigned short* A2 = (unsigned short*)alloc((size_t)NN * 256 * 2);  // [mean2|h1]
  float* res1 = (float*)alloc((size_t)NN * 128 * 4);
  float* res2 = (float*)alloc((size_t)NN * 64 * 4);
  unsigned short* Bt1 = (unsigned short*)alloc(128 * 256 * 2);
  unsigned short* Bt2 = (unsigned short*)alloc(128 * 256 * 2);
  unsigned short* Bt3 = (unsigned short*)alloc(64 * 256 * 2);
  unsigned short* Br1 = (unsigned short*)alloc(128 * 128 * 2);
  unsigned short* Br2 = (unsigned short*)alloc(64 * 128 * 2);
  unsigned short* A3 = A1;  // alias: A1 dead once res1/res2 computed and G2 output lands in A3 right half

  // zero deg + cursor (contiguous region)
  size_t zlen = (size_t)((char*)cursor - (char*)deg) + (size_t)NN * 4;
  hipMemsetAsync(deg, 0, zlen, stream);

  // CSR build
  deg_kernel<<<(NE + 255) / 256, 256, 0, stream>>>(dstn, deg);
  int nel = NN + 1;
  int nblk = (nel + 255) / 256;   // 196
  scan1_kernel<<<nblk, 256, 0, stream>>>(deg, rowoff, partials, nel, NN);
  scan2_kernel<<<1, 256, 0, stream>>>(partials, nblk);
  scan3_kernel<<<nblk, 256, 0, stream>>>(rowoff, partials, nel);
  fill_kernel<<<(NE + 255) / 256, 256, 0, stream>>>(srcn, dstn, rowoff, cursor, csr);

  // weight prep + z conversion
  prep_kernel<<<416, 256, 0, stream>>>(w1n, w1r, w2n, w2r, wfn, wfr, wr1, wr2,
                                       Bt1, Bt2, Bt3, Br1, Br2);
  convz_kernel<<<(NN * 128 / 4 + 255) / 256, 256, 0, stream>>>(z, A1);

  const int gemm_blocks = (NN + 63) / 64;  // 782
  const int agg_blocks  = (NN + 3) / 4;    // 12500

  // layer 1: mean1 = agg(z);  h1 = relu([mean1|z]@[w1n;w1r]+b1) -> A2 right half
  agg_kernel<<<agg_blocks, 256, 0, stream>>>(A1 + 128, 256, A1, 256, rowoff, csr);
  gemm_kernel<<<gemm_blocks, 256, 0, stream>>>(A1, 256, Bt1, 256, b1,
      nullptr, 0, A2 + 128, 256, nullptr, 0, NN, 128, 256, 1, 0);

  // residuals from z (A1 right half): res1 = z@wr1+br1 (f32), res2 = z@wr2+br2 (f32)
  gemm_kernel<<<gemm_blocks, 256, 0, stream>>>(A1 + 128, 256, Br1, 128, br1,
      nullptr, 0, nullptr, 0, res1, 128, NN, 128, 128, 0, 0);
  gemm_kernel<<<gemm_blocks, 256, 0, stream>>>(A1 + 128, 256, Br2, 128, br2,
      nullptr, 0, nullptr, 0, res2, 64, NN, 64, 128, 0, 0);

  // layer 2: mean2 = agg(h1);  h2 = relu([mean2|h1]@[w2n;w2r]+b2) + res1 -> A3 right half
  agg_kernel<<<agg_blocks, 256, 0, stream>>>(A2 + 128, 256, A2, 256, rowoff, csr);
  gemm_kernel<<<gemm_blocks, 256, 0, stream>>>(A2, 256, Bt2, 256, b2,
      res1, 128, A3 + 128, 256, nullptr, 0, NN, 128, 256, 1, 0);

  // layer 3: mean3 = agg(h2);  out = [mean3|h2]@[wfn;wfr]+bf + res2, sigmoid on cols 0..7
  agg_kernel<<<agg_blocks, 256, 0, stream>>>(A3 + 128, 256, A3, 256, rowoff, csr);
  gemm_kernel<<<gemm_blocks, 256, 0, stream>>>(A3, 256, Bt3, 256, bfb,
      res2, 64, nullptr, 0, out, 64, NN, 64, 256, 0, 1);
}

// Round 3
// 410.481 us; speedup vs baseline: 1.4039x; 1.0539x over previous
//
#include <hip/hip_runtime.h>
#include <hip/hip_bf16.h>
#include <math.h>

#define NN 50000
#define NE 800000

typedef short bf16x8 __attribute__((ext_vector_type(8)));
typedef float f32x4 __attribute__((ext_vector_type(4)));
typedef unsigned short us4 __attribute__((ext_vector_type(4)));
typedef unsigned short us8 __attribute__((ext_vector_type(8)));
typedef unsigned int u32x4 __attribute__((ext_vector_type(4)));

__device__ __forceinline__ float bf2f(unsigned short u) {
  union { unsigned int i; float f; } x; x.i = ((unsigned int)u) << 16; return x.f;
}
__device__ __forceinline__ unsigned short f2bf(float f) {
  union { float f; unsigned int i; } x; x.f = f;
  unsigned int i = x.i;
  unsigned int r = i + 0x7FFF + ((i >> 16) & 1);   // round-to-nearest-even
  return (unsigned short)(r >> 16);
}

// ---------------- CSR build ----------------
__global__ void deg_kernel(const int* __restrict__ dstn, int* __restrict__ deg) {
  int e = blockIdx.x * 256 + threadIdx.x;
  if (e < NE) atomicAdd(&deg[dstn[e]], 1);
}

__global__ void scan1_kernel(const int* __restrict__ deg, int* __restrict__ rowoff,
                             int* __restrict__ partials, int nel, int ndeg) {
  __shared__ int s[256];
  int t = threadIdx.x;
  int i = blockIdx.x * 256 + t;
  int v = (i < ndeg) ? deg[i] : 0;
  s[t] = v; __syncthreads();
  for (int off = 1; off < 256; off <<= 1) {
    int x = (t >= off) ? s[t - off] : 0;
    __syncthreads();
    s[t] += x;
    __syncthreads();
  }
  if (i < nel) rowoff[i] = s[t] - v;     // exclusive
  if (t == 255) partials[blockIdx.x] = s[255];
}

__global__ void scan2_kernel(int* __restrict__ partials, int nparts) {
  __shared__ int s[256];
  int t = threadIdx.x;
  int v = (t < nparts) ? partials[t] : 0;
  s[t] = v; __syncthreads();
  for (int off = 1; off < 256; off <<= 1) {
    int x = (t >= off) ? s[t - off] : 0;
    __syncthreads();
    s[t] += x;
    __syncthreads();
  }
  if (t < nparts) partials[t] = s[t] - v;  // exclusive
}

__global__ void scan3_kernel(int* __restrict__ rowoff, const int* __restrict__ partials, int nel) {
  int i = blockIdx.x * 256 + threadIdx.x;
  if (i < nel) rowoff[i] += partials[blockIdx.x];
}

__global__ void fill_kernel(const int* __restrict__ srcn, const int* __restrict__ dstn,
                            const int* __restrict__ rowoff, int* __restrict__ cursor,
                            int* __restrict__ csr) {
  int e = blockIdx.x * 256 + threadIdx.x;
  if (e >= NE) return;
  int d = dstn[e];
  int pos = atomicAdd(&cursor[d], 1);
  csr[rowoff[d] + pos] = srcn[e];
}

// ---------------- weight prep: pack B into MFMA fragment-major layout ----------
// Packed layout: frag index fi = (k0i*NT + nt)*64 + lane; 8 bf16 per frag at Bp+fi*8.
// Lane (m = lane&15, q = lane>>4) holds Bt[nt*16+m][k0i*32 + q*8 .. +7],
// i.e. W[k][n] with k = k0i*32+q*8+j, n = nt*16+m.
// Bp1 is the concatenated [w1n;w1r | 0;wr1 | 0;wr2] -> N = 128+128+64 = 320 (NT=20), K=256.
// Bp2 = [w2n;w2r] (NT=8, K=256).  Bp3 = [wfn;wfr] (NT=4, K=256).
__global__ void prep_kernel(const float* __restrict__ w1n, const float* __restrict__ w1r,
                            const float* __restrict__ w2n, const float* __restrict__ w2r,
                            const float* __restrict__ wfn, const float* __restrict__ wfr,
                            const float* __restrict__ wr1, const float* __restrict__ wr2,
                            unsigned short* __restrict__ Bp1, unsigned short* __restrict__ Bp2,
                            unsigned short* __restrict__ Bp3) {
  int g = blockIdx.x * 256 + threadIdx.x;
  unsigned short* D; int NT, fi;
  int which;  // 1,2,3
  if      (g < 10240) { fi = g;         D = Bp1; NT = 20; which = 1; }
  else if (g < 14336) { fi = g - 10240; D = Bp2; NT = 8;  which = 2; }
  else if (g < 16384) { fi = g - 14336; D = Bp3; NT = 4;  which = 3; }
  else return;
  int lane = fi & 63, t = fi >> 6;
  int nt = t % NT, k0i = t / NT;
  int m = lane & 15, q = lane >> 4;
  int kb = k0i * 32 + q * 8;          // 8-aligned: all j on same side of 128
  int n = nt * 16 + m;
  int hi = (kb >= 128);
  int k0_ = kb - (hi ? 128 : 0);
  const float* W = nullptr; int Nseg = 128; int nn = n;
  if (which == 1) {
    if (n < 128)      { W = hi ? w1r : w1n; nn = n; Nseg = 128; }
    else if (n < 256) { W = hi ? wr1 : nullptr; nn = n - 128; Nseg = 128; }
    else              { W = hi ? wr2 : nullptr; nn = n - 256; Nseg = 64; }
  } else if (which == 2) { W = hi ? w2r : w2n; Nseg = 128; }
  else                   { W = hi ? wfr : wfn; Nseg = 64; }
  unsigned short o[8];
#pragma unroll
  for (int j = 0; j < 8; j++)
    o[j] = W ? f2bf(W[(size_t)(k0_ + j) * Nseg + nn]) : (unsigned short)0;
  *(us8*)(D + (size_t)fi * 8) = *(const us8*)o;
}

// ---------------- z (f32) -> bf16 into A1 right half ----------------
__global__ void convz_kernel(const float* __restrict__ z, unsigned short* __restrict__ A1) {
  int i = blockIdx.x * 256 + threadIdx.x;   // groups of 4 elements
  if (i >= NN * 128 / 4) return;
  int i4 = i * 4;
  int row = i4 >> 7, c = i4 & 127;
  float4 v = *(const float4*)(z + i4);
  us4 o = { f2bf(v.x), f2bf(v.y), f2bf(v.z), f2bf(v.w) };
  *(us4*)(A1 + (size_t)row * 256 + 128 + c) = o;
}

// ---------------- mean aggregation: one wave per node, 4 neighbors in flight ----
__global__ __launch_bounds__(256) void agg_kernel(const unsigned short* __restrict__ feat, int fstride,
                                                  unsigned short* __restrict__ outm, int ostride,
                                                  const int* __restrict__ rowoff,
                                                  const int* __restrict__ csr) {
  int wave = threadIdx.x >> 6, lane = threadIdx.x & 63;
  int node = blockIdx.x * 4 + wave;
  if (node >= NN) return;
  int beg = rowoff[node], end = rowoff[node + 1];
  int g = lane >> 4;           // neighbor subgroup 0..3
  int c = (lane & 15) << 3;    // column offset (8 bf16 = 16B per lane)
  float a[8];
#pragma unroll
  for (int i = 0; i < 8; i++) a[i] = 0.f;
  int j = beg + g;
  for (; j + 4 < end; j += 8) {
    int s0 = csr[j];
    int s1 = csr[j + 4];
    u32x4 v0 = *(const u32x4*)(feat + (size_t)s0 * fstride + c);
    u32x4 v1 = *(const u32x4*)(feat + (size_t)s1 * fstride + c);
#pragma unroll
    for (int i = 0; i < 4; i++) {
      a[2*i]   += bf2f((unsigned short)(v0[i] & 0xffff));
      a[2*i+1] += bf2f((unsigned short)(v0[i] >> 16));
      a[2*i]   += bf2f((unsigned short)(v1[i] & 0xffff));
      a[2*i+1] += bf2f((unsigned short)(v1[i] >> 16));
    }
  }
  if (j < end) {
    int s0 = csr[j];
    u32x4 v0 = *(const u32x4*)(feat + (size_t)s0 * fstride + c);
#pragma unroll
    for (int i = 0; i < 4; i++) {
      a[2*i]   += bf2f((unsigned short)(v0[i] & 0xffff));
      a[2*i+1] += bf2f((unsigned short)(v0[i] >> 16));
    }
  }
#pragma unroll
  for (int i = 0; i < 8; i++) {
    a[i] += __shfl_xor(a[i], 16, 64);
    a[i] += __shfl_xor(a[i], 32, 64);
  }
  if (g == 0) {
    float inv = 1.f / fmaxf((float)(end - beg), 1.f);
    unsigned int o[4];
#pragma unroll
    for (int i = 0; i < 4; i++)
      o[i] = ((unsigned int)f2bf(a[2*i+1] * inv) << 16) | f2bf(a[2*i] * inv);
    *(u32x4*)(outm + (size_t)node * ostride + c) = *(const u32x4*)o;
  }
}

// ---------------- GEMM1: A1[NN x 256] @ Bp1 -> h1(relu,bf16) | res1(f32) | res2(f32) ----
// 16 rows per wave, 64 rows per block. B frags contiguous (fragment-major packed).
__global__ __launch_bounds__(256) void gemm1_kernel(
    const unsigned short* __restrict__ A,
    const unsigned short* __restrict__ Bp,
    const float* __restrict__ b1, const float* __restrict__ br1, const float* __restrict__ br2,
    unsigned short* __restrict__ h1out,   // A2+128, stride 256
    float* __restrict__ res1, float* __restrict__ res2)
{
  const int NT = 20;
  int wave = threadIdx.x >> 6, lane = threadIdx.x & 63;
  int row0 = blockIdx.x * 64 + wave * 16;
  int m = lane & 15, q = lane >> 4;
  f32x4 acc[NT];
#pragma unroll
  for (int i = 0; i < NT; i++) acc[i] = (f32x4){0.f, 0.f, 0.f, 0.f};
  const unsigned short* arow = A + (size_t)(row0 + m) * 256 + q * 8;
#pragma unroll
  for (int k0i = 0; k0i < 8; ++k0i) {
    bf16x8 af = *(const bf16x8*)(arow + k0i * 32);
    const unsigned short* bk = Bp + (size_t)k0i * NT * 512 + lane * 8;
#pragma unroll
    for (int nt = 0; nt < NT; ++nt) {
      bf16x8 bfr = *(const bf16x8*)(bk + nt * 512);
      acc[nt] = __builtin_amdgcn_mfma_f32_16x16x32_bf16(af, bfr, acc[nt], 0, 0, 0);
    }
  }
  int orow0 = row0 + q * 4;
#pragma unroll
  for (int nt = 0; nt < NT; ++nt) {
    int col = nt * 16 + m;
#pragma unroll
    for (int r = 0; r < 4; r++) {
      int row = orow0 + r;
      if (row >= NN) continue;
      float v = acc[nt][r];
      if (nt < 8) {
        v = fmaxf(v + b1[col], 0.f);
        h1out[(size_t)row * 256 + col] = f2bf(v);
      } else if (nt < 16) {
        res1[(size_t)row * 128 + (col - 128)] = v + br1[col - 128];
      } else {
        res2[(size_t)row * 64 + (col - 256)] = v + br2[col - 256];
      }
    }
  }
}

// ---------------- GEMM2/3: A[NN x 256] @ Bp -> out (+bias, +res, relu/sig8) --------
// 32 rows per wave (B frag reused 2x), 128 rows per block.
template <int NT>
__global__ __launch_bounds__(256) void gemm23_kernel(
    const unsigned short* __restrict__ A,
    const unsigned short* __restrict__ Bp,
    const float* __restrict__ bias,
    const float* __restrict__ res, int res_stride,
    unsigned short* __restrict__ out_bf,   // stride 256, may be null
    float* __restrict__ out_f, int of_stride,
    int relu, int sig8)
{
  int wave = threadIdx.x >> 6, lane = threadIdx.x & 63;
  int row0 = blockIdx.x * 128 + wave * 32;
  int m = lane & 15, q = lane >> 4;
  f32x4 acc[2][NT];
#pragma unroll
  for (int h = 0; h < 2; h++)
#pragma unroll
    for (int i = 0; i < NT; i++) acc[h][i] = (f32x4){0.f, 0.f, 0.f, 0.f};
  const unsigned short* arow0 = A + (size_t)(row0 + m) * 256 + q * 8;
  const unsigned short* arow1 = arow0 + 16 * 256;
#pragma unroll
  for (int k0i = 0; k0i < 8; ++k0i) {
    bf16x8 af0 = *(const bf16x8*)(arow0 + k0i * 32);
    bf16x8 af1 = *(const bf16x8*)(arow1 + k0i * 32);
    const unsigned short* bk = Bp + (size_t)k0i * NT * 512 + lane * 8;
#pragma unroll
    for (int nt = 0; nt < NT; ++nt) {
      bf16x8 bfr = *(const bf16x8*)(bk + nt * 512);
      acc[0][nt] = __builtin_amdgcn_mfma_f32_16x16x32_bf16(af0, bfr, acc[0][nt], 0, 0, 0);
      acc[1][nt] = __builtin_amdgcn_mfma_f32_16x16x32_bf16(af1, bfr, acc[1][nt], 0, 0, 0);
    }
  }
#pragma unroll
  for (int h = 0; h < 2; h++) {
    int orow0 = row0 + h * 16 + q * 4;
#pragma unroll
    for (int nt = 0; nt < NT; ++nt) {
      int col = nt * 16 + m;
      float bb = bias[col];
#pragma unroll
      for (int r = 0; r < 4; r++) {
        int row = orow0 + r;
        if (row >= NN) continue;
        float v = acc[h][nt][r] + bb;
        if (relu) v = fmaxf(v, 0.f);
        if (res)  v += res[(size_t)row * res_stride + col];
        if (sig8 && col < 8) v = 1.f / (1.f + __expf(-v));
        if (out_bf) out_bf[(size_t)row * 256 + col] = f2bf(v);
        if (out_f)  out_f[(size_t)row * of_stride + col] = v;
      }
    }
  }
}

extern "C" void kernel_launch(void* const* d_in, const int* in_sizes, int n_in,
                              void* d_out, int out_size, void* d_ws, size_t ws_size,
                              hipStream_t stream) {
  const float* z   = (const float*)d_in[0];
  const int*   edge = (const int*)d_in[1];
  const int*   srcn = edge;        // edge_index[0]
  const int*   dstn = edge + NE;   // edge_index[1]
  const float* w1n = (const float*)d_in[2];
  const float* w1r = (const float*)d_in[3];
  const float* b1  = (const float*)d_in[4];
  const float* w2n = (const float*)d_in[5];
  const float* w2r = (const float*)d_in[6];
  const float* b2  = (const float*)d_in[7];
  const float* wfn = (const float*)d_in[8];
  const float* wfr = (const float*)d_in[9];
  const float* bfb = (const float*)d_in[10];
  const float* wr1 = (const float*)d_in[11];
  const float* br1 = (const float*)d_in[12];
  const float* wr2 = (const float*)d_in[13];
  const float* br2 = (const float*)d_in[14];
  float* out = (float*)d_out;

  char* p = (char*)d_ws;
  auto alloc = [&](size_t bytes) { char* r = p; p += (bytes + 255) & ~255ull; return r; };
  int* deg    = (int*)alloc((size_t)NN * 4);
  int* cursor = (int*)alloc((size_t)NN * 4);
  int* rowoff = (int*)alloc((size_t)(NN + 1) * 4);
  int* partials = (int*)alloc(256 * 4);
  int* csr    = (int*)alloc((size_t)NE * 4);
  unsigned short* A1 = (unsigned short*)alloc((size_t)NN * 256 * 2);  // [mean1|z_bf], later reused as A3
  unsigned short* A2 = (unsigned short*)alloc((size_t)NN * 256 * 2);  // [mean2|h1]
  float* res1 = (float*)alloc((size_t)NN * 128 * 4);
  float* res2 = (float*)alloc((size_t)NN * 64 * 4);
  unsigned short* Bp1 = (unsigned short*)alloc(10240 * 8 * 2);
  unsigned short* Bp2 = (unsigned short*)alloc(4096 * 8 * 2);
  unsigned short* Bp3 = (unsigned short*)alloc(2048 * 8 * 2);
  unsigned short* A3 = A1;  // alias: A1 dead once gemm1 outputs land

  // zero deg + cursor (contiguous region)
  size_t zlen = (size_t)((char*)cursor - (char*)deg) + (size_t)NN * 4;
  hipMemsetAsync(deg, 0, zlen, stream);

  // CSR build
  deg_kernel<<<(NE + 255) / 256, 256, 0, stream>>>(dstn, deg);
  int nel = NN + 1;
  int nblk = (nel + 255) / 256;   // 196
  scan1_kernel<<<nblk, 256, 0, stream>>>(deg, rowoff, partials, nel, NN);
  scan2_kernel<<<1, 256, 0, stream>>>(partials, nblk);
  scan3_kernel<<<nblk, 256, 0, stream>>>(rowoff, partials, nel);
  fill_kernel<<<(NE + 255) / 256, 256, 0, stream>>>(srcn, dstn, rowoff, cursor, csr);

  // weight prep + z conversion
  prep_kernel<<<64, 256, 0, stream>>>(w1n, w1r, w2n, w2r, wfn, wfr, wr1, wr2, Bp1, Bp2, Bp3);
  convz_kernel<<<(NN * 128 / 4 + 255) / 256, 256, 0, stream>>>(z, A1);

  const int g1_blocks  = (NN + 63) / 64;    // 782
  const int g23_blocks = (NN + 127) / 128;  // 391
  const int agg_blocks = (NN + 3) / 4;      // 12500

  // layer 1: mean1 = agg(z); then one fused GEMM -> h1 (A2 right), res1, res2
  agg_kernel<<<agg_blocks, 256, 0, stream>>>(A1 + 128, 256, A1, 256, rowoff, csr);
  gemm1_kernel<<<g1_blocks, 256, 0, stream>>>(A1, Bp1, b1, br1, br2, A2 + 128, res1, res2);

  // layer 2: mean2 = agg(h1); h2 = relu([mean2|h1]@W2+b2) + res1 -> A3 right
  agg_kernel<<<agg_blocks, 256, 0, stream>>>(A2 + 128, 256, A2, 256, rowoff, csr);
  gemm23_kernel<8><<<g23_blocks, 256, 0, stream>>>(A2, Bp2, b2, res1, 128,
      A3 + 128, nullptr, 0, 1, 0);

  // layer 3: mean3 = agg(h2); out = [mean3|h2]@Wf+bf + res2, sigmoid cols 0..7
  agg_kernel<<<agg_blocks, 256, 0, stream>>>(A3 + 128, 256, A3, 256, rowoff, csr);
  gemm23_kernel<4><<<g23_blocks, 256, 0, stream>>>(A3, Bp3, bfb, res2, 64,
      nullptr, out, 64, 0, 1);
}

// Round 4
// 362.757 us; speedup vs baseline: 1.5886x; 1.1316x over previous
//
#include <hip/hip_runtime.h>
#include <hip/hip_bf16.h>
#include <math.h>

#define NN 50000
#define NE 800000

typedef short bf16x8 __attribute__((ext_vector_type(8)));
typedef float f32x4 __attribute__((ext_vector_type(4)));
typedef unsigned short us4 __attribute__((ext_vector_type(4)));
typedef unsigned short us8 __attribute__((ext_vector_type(8)));
typedef unsigned int u32x4 __attribute__((ext_vector_type(4)));

__device__ __forceinline__ float bf2f(unsigned short u) {
  union { unsigned int i; float f; } x; x.i = ((unsigned int)u) << 16; return x.f;
}
__device__ __forceinline__ unsigned short f2bf(float f) {
  union { float f; unsigned int i; } x; x.f = f;
  unsigned int i = x.i;
  unsigned int r = i + 0x7FFF + ((i >> 16) & 1);   // round-to-nearest-even
  return (unsigned short)(r >> 16);
}

// ---------------- CSR build ----------------
__global__ void deg_kernel(const int* __restrict__ dstn, int* __restrict__ deg) {
  int e = blockIdx.x * 256 + threadIdx.x;
  if (e < NE) atomicAdd(&deg[dstn[e]], 1);
}

__global__ void scan1_kernel(const int* __restrict__ deg, int* __restrict__ rowoff,
                             int* __restrict__ partials, int nel, int ndeg) {
  __shared__ int s[256];
  int t = threadIdx.x;
  int i = blockIdx.x * 256 + t;
  int v = (i < ndeg) ? deg[i] : 0;
  s[t] = v; __syncthreads();
  for (int off = 1; off < 256; off <<= 1) {
    int x = (t >= off) ? s[t - off] : 0;
    __syncthreads();
    s[t] += x;
    __syncthreads();
  }
  if (i < nel) rowoff[i] = s[t] - v;     // exclusive
  if (t == 255) partials[blockIdx.x] = s[255];
}

__global__ void scan2_kernel(int* __restrict__ partials, int nparts) {
  __shared__ int s[256];
  int t = threadIdx.x;
  int v = (t < nparts) ? partials[t] : 0;
  s[t] = v; __syncthreads();
  for (int off = 1; off < 256; off <<= 1) {
    int x = (t >= off) ? s[t - off] : 0;
    __syncthreads();
    s[t] += x;
    __syncthreads();
  }
  if (t < nparts) partials[t] = s[t] - v;  // exclusive
}

__global__ void scan3_kernel(int* __restrict__ rowoff, const int* __restrict__ partials, int nel) {
  int i = blockIdx.x * 256 + threadIdx.x;
  if (i < nel) rowoff[i] += partials[blockIdx.x];
}

__global__ void fill_kernel(const int* __restrict__ srcn, const int* __restrict__ dstn,
                            const int* __restrict__ rowoff, int* __restrict__ cursor,
                            int* __restrict__ csr) {
  int e = blockIdx.x * 256 + threadIdx.x;
  if (e >= NE) return;
  int d = dstn[e];
  int pos = atomicAdd(&cursor[d], 1);
  csr[rowoff[d] + pos] = srcn[e];
}

// ---------------- weight prep: pack B into MFMA fragment-major layout ----------
// frag index fi = (k0i*NT + nt)*64 + lane; 8 bf16 per frag at Bp+fi*8.
// Lane (m=lane&15, q=lane>>4) holds W[k][n], k = k0i*32+q*8+j, n = nt*16+m.
// Bp1 = [w1n;w1r | 0;wr1 | 0;wr2], N=320 (NT=20), K=256.
// Bp2 = [w2n;w2r] (NT=8).  Bp3 = [wfn;wfr] (NT=4).
__global__ void prep_kernel(const float* __restrict__ w1n, const float* __restrict__ w1r,
                            const float* __restrict__ w2n, const float* __restrict__ w2r,
                            const float* __restrict__ wfn, const float* __restrict__ wfr,
                            const float* __restrict__ wr1, const float* __restrict__ wr2,
                            unsigned short* __restrict__ Bp1, unsigned short* __restrict__ Bp2,
                            unsigned short* __restrict__ Bp3) {
  int g = blockIdx.x * 256 + threadIdx.x;
  unsigned short* D; int NT, fi;
  int which;  // 1,2,3
  if      (g < 10240) { fi = g;         D = Bp1; NT = 20; which = 1; }
  else if (g < 14336) { fi = g - 10240; D = Bp2; NT = 8;  which = 2; }
  else if (g < 16384) { fi = g - 14336; D = Bp3; NT = 4;  which = 3; }
  else return;
  int lane = fi & 63, t = fi >> 6;
  int nt = t % NT, k0i = t / NT;
  int m = lane & 15, q = lane >> 4;
  int kb = k0i * 32 + q * 8;          // 8-aligned: all j on same side of 128
  int n = nt * 16 + m;
  int hi = (kb >= 128);
  int k0_ = kb - (hi ? 128 : 0);
  const float* W = nullptr; int Nseg = 128; int nn = n;
  if (which == 1) {
    if (n < 128)      { W = hi ? w1r : w1n; nn = n; Nseg = 128; }
    else if (n < 256) { W = hi ? wr1 : nullptr; nn = n - 128; Nseg = 128; }
    else              { W = hi ? wr2 : nullptr; nn = n - 256; Nseg = 64; }
  } else if (which == 2) { W = hi ? w2r : w2n; Nseg = 128; }
  else                   { W = hi ? wfr : wfn; Nseg = 64; }
  unsigned short o[8];
#pragma unroll
  for (int j = 0; j < 8; j++)
    o[j] = W ? f2bf(W[(size_t)(k0_ + j) * Nseg + nn]) : (unsigned short)0;
  *(us8*)(D + (size_t)fi * 8) = *(const us8*)o;
}

// ---------------- z (f32) -> bf16 into A1 right half ----------------
__global__ void convz_kernel(const float* __restrict__ z, unsigned short* __restrict__ A1) {
  int i = blockIdx.x * 256 + threadIdx.x;   // groups of 4 elements
  if (i >= NN * 128 / 4) return;
  int i4 = i * 4;
  int row = i4 >> 7, c = i4 & 127;
  float4 v = *(const float4*)(z + i4);
  us4 o = { f2bf(v.x), f2bf(v.y), f2bf(v.z), f2bf(v.w) };
  *(us4*)(A1 + (size_t)row * 256 + 128 + c) = o;
}

// ---------------- mean aggregation: one wave per node, 4 subgroups x 4-deep MLP --
__global__ __launch_bounds__(256) void agg_kernel(const unsigned short* __restrict__ feat, int fstride,
                                                  unsigned short* __restrict__ outm, int ostride,
                                                  const int* __restrict__ rowoff,
                                                  const int* __restrict__ csr) {
  int wave = threadIdx.x >> 6, lane = threadIdx.x & 63;
  int node = blockIdx.x * 4 + wave;
  if (node >= NN) return;
  int beg = rowoff[node], end = rowoff[node + 1];
  int g = lane >> 4;           // neighbor subgroup 0..3
  int c = (lane & 15) << 3;    // column offset (8 bf16 = 16B per lane)
  float a[8];
#pragma unroll
  for (int i = 0; i < 8; i++) a[i] = 0.f;
  int j = beg + g;
  for (; j + 12 < end; j += 16) {   // 4 row-reads in flight per subgroup
    int s0 = csr[j];
    int s1 = csr[j + 4];
    int s2 = csr[j + 8];
    int s3 = csr[j + 12];
    u32x4 v0 = *(const u32x4*)(feat + (size_t)s0 * fstride + c);
    u32x4 v1 = *(const u32x4*)(feat + (size_t)s1 * fstride + c);
    u32x4 v2 = *(const u32x4*)(feat + (size_t)s2 * fstride + c);
    u32x4 v3 = *(const u32x4*)(feat + (size_t)s3 * fstride + c);
#pragma unroll
    for (int i = 0; i < 4; i++) {
      a[2*i]   += bf2f((unsigned short)(v0[i] & 0xffff)) + bf2f((unsigned short)(v1[i] & 0xffff))
                + bf2f((unsigned short)(v2[i] & 0xffff)) + bf2f((unsigned short)(v3[i] & 0xffff));
      a[2*i+1] += bf2f((unsigned short)(v0[i] >> 16)) + bf2f((unsigned short)(v1[i] >> 16))
                + bf2f((unsigned short)(v2[i] >> 16)) + bf2f((unsigned short)(v3[i] >> 16));
    }
  }
  for (; j < end; j += 4) {
    int s0 = csr[j];
    u32x4 v0 = *(const u32x4*)(feat + (size_t)s0 * fstride + c);
#pragma unroll
    for (int i = 0; i < 4; i++) {
      a[2*i]   += bf2f((unsigned short)(v0[i] & 0xffff));
      a[2*i+1] += bf2f((unsigned short)(v0[i] >> 16));
    }
  }
#pragma unroll
  for (int i = 0; i < 8; i++) {
    a[i] += __shfl_xor(a[i], 16, 64);
    a[i] += __shfl_xor(a[i], 32, 64);
  }
  if (g == 0) {
    float inv = 1.f / fmaxf((float)(end - beg), 1.f);
    unsigned int o[4];
#pragma unroll
    for (int i = 0; i < 4; i++)
      o[i] = ((unsigned int)f2bf(a[2*i+1] * inv) << 16) | f2bf(a[2*i] * inv);
    *(u32x4*)(outm + (size_t)node * ostride + c) = *(const u32x4*)o;
  }
}

// ---------------- GEMM1: A1[NN x 256] @ Bp1(NT=20) -> h1 | res1 | res2 ----------
// grid (782, 5): blockIdx.y picks 4 output tiles; uniform epilogue mode per block.
__global__ __launch_bounds__(256) void gemm1_kernel(
    const unsigned short* __restrict__ A,
    const unsigned short* __restrict__ Bp,
    const float* __restrict__ b1, const float* __restrict__ br1, const float* __restrict__ br2,
    unsigned short* __restrict__ h1out,   // A2+128, stride 256
    unsigned short* __restrict__ res1, unsigned short* __restrict__ res2)
{
  const int NT = 20;
  int wave = threadIdx.x >> 6, lane = threadIdx.x & 63;
  int row0 = blockIdx.x * 64 + wave * 16;
  int m = lane & 15, q = lane >> 4;
  int ybase = blockIdx.y * 4;
  f32x4 acc[4];
#pragma unroll
  for (int i = 0; i < 4; i++) acc[i] = (f32x4){0.f, 0.f, 0.f, 0.f};
  const unsigned short* arow = A + (size_t)(row0 + m) * 256 + q * 8;
  bf16x8 af[8];
#pragma unroll
  for (int k0i = 0; k0i < 8; ++k0i) af[k0i] = *(const bf16x8*)(arow + k0i * 32);
#pragma unroll
  for (int k0i = 0; k0i < 8; ++k0i) {
    const unsigned short* bk = Bp + ((size_t)k0i * NT + ybase) * 512 + lane * 8;
#pragma unroll
    for (int s = 0; s < 4; ++s) {
      bf16x8 bfr = *(const bf16x8*)(bk + s * 512);
      acc[s] = __builtin_amdgcn_mfma_f32_16x16x32_bf16(af[k0i], bfr, acc[s], 0, 0, 0);
    }
  }
  int orow0 = row0 + q * 4;
#pragma unroll
  for (int s = 0; s < 4; ++s) {
    int nt = ybase + s;
    int col = nt * 16 + m;
#pragma unroll
    for (int r = 0; r < 4; r++) {
      int row = orow0 + r;
      if (row >= NN) continue;
      float v = acc[s][r];
      if (blockIdx.y < 2) {
        h1out[(size_t)row * 256 + col] = f2bf(fmaxf(v + b1[col], 0.f));
      } else if (blockIdx.y < 4) {
        res1[(size_t)row * 128 + (col - 128)] = f2bf(v + br1[col - 128]);
      } else {
        res2[(size_t)row * 64 + (col - 256)] = f2bf(v + br2[col - 256]);
      }
    }
  }
}

// ---------------- GEMM2/3: A[NN x 256] @ Bp -> out (+bias, +res(bf16), relu/sig8) -
// 32 rows per wave, 128 rows per block; grid.y splits N into groups of 4 tiles.
template <int NTT>
__global__ __launch_bounds__(256) void gemm23_kernel(
    const unsigned short* __restrict__ A,
    const unsigned short* __restrict__ Bp,
    const float* __restrict__ bias,
    const unsigned short* __restrict__ res, int res_stride,
    unsigned short* __restrict__ out_bf,   // stride 256, may be null
    float* __restrict__ out_f, int of_stride,
    int relu, int sig8)
{
  int wave = threadIdx.x >> 6, lane = threadIdx.x & 63;
  int row0 = blockIdx.x * 128 + wave * 32;
  int m = lane & 15, q = lane >> 4;
  int ybase = blockIdx.y * 4;
  f32x4 acc[2][4];
#pragma unroll
  for (int h = 0; h < 2; h++)
#pragma unroll
    for (int i = 0; i < 4; i++) acc[h][i] = (f32x4){0.f, 0.f, 0.f, 0.f};
  const unsigned short* arow0 = A + (size_t)(row0 + m) * 256 + q * 8;
  const unsigned short* arow1 = arow0 + 16 * 256;
  bf16x8 af0[8], af1[8];
#pragma unroll
  for (int k0i = 0; k0i < 8; ++k0i) {
    af0[k0i] = *(const bf16x8*)(arow0 + k0i * 32);
    af1[k0i] = *(const bf16x8*)(arow1 + k0i * 32);
  }
#pragma unroll
  for (int k0i = 0; k0i < 8; ++k0i) {
    const unsigned short* bk = Bp + ((size_t)k0i * NTT + ybase) * 512 + lane * 8;
#pragma unroll
    for (int s = 0; s < 4; ++s) {
      bf16x8 bfr = *(const bf16x8*)(bk + s * 512);
      acc[0][s] = __builtin_amdgcn_mfma_f32_16x16x32_bf16(af0[k0i], bfr, acc[0][s], 0, 0, 0);
      acc[1][s] = __builtin_amdgcn_mfma_f32_16x16x32_bf16(af1[k0i], bfr, acc[1][s], 0, 0, 0);
    }
  }
#pragma unroll
  for (int h = 0; h < 2; h++) {
    int orow0 = row0 + h * 16 + q * 4;
#pragma unroll
    for (int s = 0; s < 4; ++s) {
      int col = (ybase + s) * 16 + m;
      float bb = bias[col];
#pragma unroll
      for (int r = 0; r < 4; r++) {
        int row = orow0 + r;
        if (row >= NN) continue;
        float v = acc[h][s][r] + bb;
        if (relu) v = fmaxf(v, 0.f);
        if (res)  v += bf2f(res[(size_t)row * res_stride + col]);
        if (sig8 && col < 8) v = 1.f / (1.f + __expf(-v));
        if (out_bf) out_bf[(size_t)row * 256 + col] = f2bf(v);
        if (out_f)  out_f[(size_t)row * of_stride + col] = v;
      }
    }
  }
}

extern "C" void kernel_launch(void* const* d_in, const int* in_sizes, int n_in,
                              void* d_out, int out_size, void* d_ws, size_t ws_size,
                              hipStream_t stream) {
  const float* z   = (const float*)d_in[0];
  const int*   edge = (const int*)d_in[1];
  const int*   srcn = edge;        // edge_index[0]
  const int*   dstn = edge + NE;   // edge_index[1]
  const float* w1n = (const float*)d_in[2];
  const float* w1r = (const float*)d_in[3];
  const float* b1  = (const float*)d_in[4];
  const float* w2n = (const float*)d_in[5];
  const float* w2r = (const float*)d_in[6];
  const float* b2  = (const float*)d_in[7];
  const float* wfn = (const float*)d_in[8];
  const float* wfr = (const float*)d_in[9];
  const float* bfb = (const float*)d_in[10];
  const float* wr1 = (const float*)d_in[11];
  const float* br1 = (const float*)d_in[12];
  const float* wr2 = (const float*)d_in[13];
  const float* br2 = (const float*)d_in[14];
  float* out = (float*)d_out;

  char* p = (char*)d_ws;
  auto alloc = [&](size_t bytes) { char* r = p; p += (bytes + 255) & ~255ull; return r; };
  int* deg    = (int*)alloc((size_t)NN * 4);
  int* cursor = (int*)alloc((size_t)NN * 4);
  int* rowoff = (int*)alloc((size_t)(NN + 1) * 4);
  int* partials = (int*)alloc(256 * 4);
  int* csr    = (int*)alloc((size_t)NE * 4);
  unsigned short* A1 = (unsigned short*)alloc((size_t)NN * 256 * 2);  // [mean1|z_bf], later reused as A3
  unsigned short* A2 = (unsigned short*)alloc((size_t)NN * 256 * 2);  // [mean2|h1]
  unsigned short* res1 = (unsigned short*)alloc((size_t)NN * 128 * 2);
  unsigned short* res2 = (unsigned short*)alloc((size_t)NN * 64 * 2);
  unsigned short* Bp1 = (unsigned short*)alloc(10240 * 8 * 2);
  unsigned short* Bp2 = (unsigned short*)alloc(4096 * 8 * 2);
  unsigned short* Bp3 = (unsigned short*)alloc(2048 * 8 * 2);
  unsigned short* A3 = A1;  // alias: A1 dead once gemm1 outputs land

  // zero deg + cursor (contiguous region)
  size_t zlen = (size_t)((char*)cursor - (char*)deg) + (size_t)NN * 4;
  hipMemsetAsync(deg, 0, zlen, stream);

  // CSR build
  deg_kernel<<<(NE + 255) / 256, 256, 0, stream>>>(dstn, deg);
  int nel = NN + 1;
  int nblk = (nel + 255) / 256;   // 196
  scan1_kernel<<<nblk, 256, 0, stream>>>(deg, rowoff, partials, nel, NN);
  scan2_kernel<<<1, 256, 0, stream>>>(partials, nblk);
  scan3_kernel<<<nblk, 256, 0, stream>>>(rowoff, partials, nel);
  fill_kernel<<<(NE + 255) / 256, 256, 0, stream>>>(srcn, dstn, rowoff, cursor, csr);

  // weight prep + z conversion
  prep_kernel<<<64, 256, 0, stream>>>(w1n, w1r, w2n, w2r, wfn, wfr, wr1, wr2, Bp1, Bp2, Bp3);
  convz_kernel<<<(NN * 128 / 4 + 255) / 256, 256, 0, stream>>>(z, A1);

  const int g1x  = (NN + 63) / 64;    // 782
  const int g23x = (NN + 127) / 128;  // 391
  const int agg_blocks = (NN + 3) / 4;  // 12500

  // layer 1: mean1 = agg(z); fused GEMM -> h1 (A2 right), res1, res2 (bf16)
  agg_kernel<<<agg_blocks, 256, 0, stream>>>(A1 + 128, 256, A1, 256, rowoff, csr);
  gemm1_kernel<<<dim3(g1x, 5), 256, 0, stream>>>(A1, Bp1, b1, br1, br2, A2 + 128, res1, res2);

  // layer 2: mean2 = agg(h1); h2 = relu([mean2|h1]@W2+b2) + res1 -> A3 right
  agg_kernel<<<agg_blocks, 256, 0, stream>>>(A2 + 128, 256, A2, 256, rowoff, csr);
  gemm23_kernel<8><<<dim3(g23x, 2), 256, 0, stream>>>(A2, Bp2, b2, res1, 128,
      A3 + 128, nullptr, 0, 1, 0);

  // layer 3: mean3 = agg(h2); out = [mean3|h2]@Wf+bf + res2, sigmoid cols 0..7
  agg_kernel<<<agg_blocks, 256, 0, stream>>>(A3 + 128, 256, A3, 256, rowoff, csr);
  gemm23_kernel<4><<<dim3(g23x, 1), 256, 0, stream>>>(A3, Bp3, bfb, res2, 64,
      nullptr, out, 64, 0, 1);
}

// Round 5
// 359.781 us; speedup vs baseline: 1.6017x; 1.0083x over previous
//
#include <hip/hip_runtime.h>
#include <hip/hip_bf16.h>
#include <math.h>

#define NN 50000
#define NE 800000

typedef short bf16x8 __attribute__((ext_vector_type(8)));
typedef float f32x4 __attribute__((ext_vector_type(4)));
typedef unsigned short us4 __attribute__((ext_vector_type(4)));
typedef unsigned short us8 __attribute__((ext_vector_type(8)));
typedef unsigned int u32x4 __attribute__((ext_vector_type(4)));

__device__ __forceinline__ float bf2f(unsigned short u) {
  union { unsigned int i; float f; } x; x.i = ((unsigned int)u) << 16; return x.f;
}
__device__ __forceinline__ unsigned short f2bf(float f) {
  union { float f; unsigned int i; } x; x.f = f;
  unsigned int i = x.i;
  unsigned int r = i + 0x7FFF + ((i >> 16) & 1);   // round-to-nearest-even
  return (unsigned short)(r >> 16);
}
__device__ __forceinline__ us4 pack4(f32x4 v) {
  us4 o; o[0] = f2bf(v[0]); o[1] = f2bf(v[1]); o[2] = f2bf(v[2]); o[3] = f2bf(v[3]);
  return o;
}

// ---------------- CSR build ----------------
__global__ void deg_kernel(const int* __restrict__ dstn, int* __restrict__ deg) {
  int e = blockIdx.x * 256 + threadIdx.x;
  if (e < NE) atomicAdd(&deg[dstn[e]], 1);
}

__global__ void scan1_kernel(const int* __restrict__ deg, int* __restrict__ rowoff,
                             int* __restrict__ partials, int nel, int ndeg) {
  __shared__ int s[256];
  int t = threadIdx.x;
  int i = blockIdx.x * 256 + t;
  int v = (i < ndeg) ? deg[i] : 0;
  s[t] = v; __syncthreads();
  for (int off = 1; off < 256; off <<= 1) {
    int x = (t >= off) ? s[t - off] : 0;
    __syncthreads();
    s[t] += x;
    __syncthreads();
  }
  if (i < nel) rowoff[i] = s[t] - v;     // exclusive
  if (t == 255) partials[blockIdx.x] = s[255];
}

__global__ void scan2_kernel(int* __restrict__ partials, int nparts) {
  __shared__ int s[256];
  int t = threadIdx.x;
  int v = (t < nparts) ? partials[t] : 0;
  s[t] = v; __syncthreads();
  for (int off = 1; off < 256; off <<= 1) {
    int x = (t >= off) ? s[t - off] : 0;
    __syncthreads();
    s[t] += x;
    __syncthreads();
  }
  if (t < nparts) partials[t] = s[t] - v;  // exclusive
}

__global__ void scan3_kernel(int* __restrict__ rowoff, const int* __restrict__ partials, int nel) {
  int i = blockIdx.x * 256 + threadIdx.x;
  if (i < nel) rowoff[i] += partials[blockIdx.x];
}

__global__ void fill_kernel(const int* __restrict__ srcn, const int* __restrict__ dstn,
                            const int* __restrict__ rowoff, int* __restrict__ cursor,
                            int* __restrict__ csr) {
  int e = blockIdx.x * 256 + threadIdx.x;
  if (e >= NE) return;
  int d = dstn[e];
  int pos = atomicAdd(&cursor[d], 1);
  csr[rowoff[d] + pos] = srcn[e];
}

// ---------------- weight prep: pack B into MFMA fragment-major layout ----------
// frag index fi = (k0i*NT + nt)*64 + lane; 8 bf16 per frag at Bp+fi*8.
// Lane (m=lane&15, q=lane>>4) holds W[k][n], k = k0i*32+q*8+j, n = nt*16+m.
// Bp1 = [w1n;w1r | 0;wr1 | 0;wr2], N=320 (NT=20), K=256.
// Bp2 = [w2n;w2r] (NT=8).  Bp3 = [wfn;wfr] (NT=4).
__global__ void prep_kernel(const float* __restrict__ w1n, const float* __restrict__ w1r,
                            const float* __restrict__ w2n, const float* __restrict__ w2r,
                            const float* __restrict__ wfn, const float* __restrict__ wfr,
                            const float* __restrict__ wr1, const float* __restrict__ wr2,
                            unsigned short* __restrict__ Bp1, unsigned short* __restrict__ Bp2,
                            unsigned short* __restrict__ Bp3) {
  int g = blockIdx.x * 256 + threadIdx.x;
  unsigned short* D; int NT, fi;
  int which;  // 1,2,3
  if      (g < 10240) { fi = g;         D = Bp1; NT = 20; which = 1; }
  else if (g < 14336) { fi = g - 10240; D = Bp2; NT = 8;  which = 2; }
  else if (g < 16384) { fi = g - 14336; D = Bp3; NT = 4;  which = 3; }
  else return;
  int lane = fi & 63, t = fi >> 6;
  int nt = t % NT, k0i = t / NT;
  int m = lane & 15, q = lane >> 4;
  int kb = k0i * 32 + q * 8;          // 8-aligned: all j on same side of 128
  int n = nt * 16 + m;
  int hi = (kb >= 128);
  int k0_ = kb - (hi ? 128 : 0);
  const float* W = nullptr; int Nseg = 128; int nn = n;
  if (which == 1) {
    if (n < 128)      { W = hi ? w1r : w1n; nn = n; Nseg = 128; }
    else if (n < 256) { W = hi ? wr1 : nullptr; nn = n - 128; Nseg = 128; }
    else              { W = hi ? wr2 : nullptr; nn = n - 256; Nseg = 64; }
  } else if (which == 2) { W = hi ? w2r : w2n; Nseg = 128; }
  else                   { W = hi ? wfr : wfn; Nseg = 64; }
  unsigned short o[8];
#pragma unroll
  for (int j = 0; j < 8; j++)
    o[j] = W ? f2bf(W[(size_t)(k0_ + j) * Nseg + nn]) : (unsigned short)0;
  *(us8*)(D + (size_t)fi * 8) = *(const us8*)o;
}

// ---------------- z (f32) -> bf16 into A1 right half ----------------
__global__ void convz_kernel(const float* __restrict__ z, unsigned short* __restrict__ A1) {
  int i = blockIdx.x * 256 + threadIdx.x;   // groups of 4 elements
  if (i >= NN * 128 / 4) return;
  int i4 = i * 4;
  int row = i4 >> 7, c = i4 & 127;
  float4 v = *(const float4*)(z + i4);
  us4 o = { f2bf(v.x), f2bf(v.y), f2bf(v.z), f2bf(v.w) };
  *(us4*)(A1 + (size_t)row * 256 + 128 + c) = o;
}

// ---------------- mean aggregation: one wave per node, 4 subgroups x 4-deep MLP --
__global__ __launch_bounds__(256) void agg_kernel(const unsigned short* __restrict__ feat, int fstride,
                                                  unsigned short* __restrict__ outm, int ostride,
                                                  const int* __restrict__ rowoff,
                                                  const int* __restrict__ csr) {
  int wave = threadIdx.x >> 6, lane = threadIdx.x & 63;
  int node = blockIdx.x * 4 + wave;
  if (node >= NN) return;
  int beg = rowoff[node], end = rowoff[node + 1];
  int g = lane >> 4;           // neighbor subgroup 0..3
  int c = (lane & 15) << 3;    // column offset (8 bf16 = 16B per lane)
  float a[8];
#pragma unroll
  for (int i = 0; i < 8; i++) a[i] = 0.f;
  int j = beg + g;
  for (; j + 12 < end; j += 16) {   // 4 row-reads in flight per subgroup
    int s0 = csr[j];
    int s1 = csr[j + 4];
    int s2 = csr[j + 8];
    int s3 = csr[j + 12];
    u32x4 v0 = *(const u32x4*)(feat + (size_t)s0 * fstride + c);
    u32x4 v1 = *(const u32x4*)(feat + (size_t)s1 * fstride + c);
    u32x4 v2 = *(const u32x4*)(feat + (size_t)s2 * fstride + c);
    u32x4 v3 = *(const u32x4*)(feat + (size_t)s3 * fstride + c);
#pragma unroll
    for (int i = 0; i < 4; i++) {
      a[2*i]   += bf2f((unsigned short)(v0[i] & 0xffff)) + bf2f((unsigned short)(v1[i] & 0xffff))
                + bf2f((unsigned short)(v2[i] & 0xffff)) + bf2f((unsigned short)(v3[i] & 0xffff));
      a[2*i+1] += bf2f((unsigned short)(v0[i] >> 16)) + bf2f((unsigned short)(v1[i] >> 16))
                + bf2f((unsigned short)(v2[i] >> 16)) + bf2f((unsigned short)(v3[i] >> 16));
    }
  }
  for (; j < end; j += 4) {
    int s0 = csr[j];
    u32x4 v0 = *(const u32x4*)(feat + (size_t)s0 * fstride + c);
#pragma unroll
    for (int i = 0; i < 4; i++) {
      a[2*i]   += bf2f((unsigned short)(v0[i] & 0xffff));
      a[2*i+1] += bf2f((unsigned short)(v0[i] >> 16));
    }
  }
#pragma unroll
  for (int i = 0; i < 8; i++) {
    a[i] += __shfl_xor(a[i], 16, 64);
    a[i] += __shfl_xor(a[i], 32, 64);
  }
  if (g == 0) {
    float inv = 1.f / fmaxf((float)(end - beg), 1.f);
    unsigned int o[4];
#pragma unroll
    for (int i = 0; i < 4; i++)
      o[i] = ((unsigned int)f2bf(a[2*i+1] * inv) << 16) | f2bf(a[2*i] * inv);
    *(u32x4*)(outm + (size_t)node * ostride + c) = *(const u32x4*)o;
  }
}

// ---------------- GEMM1: A1[NN x 256] @ Bp1(NT=20) -> h1 | res1 | res2 ----------
// grid (782, 2): y picks 10 tiles. Swapped-operand MFMA: acc holds C^T, so each
// lane has row = lane&15, cols q*4+reg -> packed 8B bf16 stores.
__global__ __launch_bounds__(256) void gemm1_kernel(
    const unsigned short* __restrict__ A,
    const unsigned short* __restrict__ Bp,
    const float* __restrict__ b1, const float* __restrict__ br1, const float* __restrict__ br2,
    unsigned short* __restrict__ h1out,   // A2+128, stride 256
    unsigned short* __restrict__ res1, unsigned short* __restrict__ res2)
{
  const int NT = 20;
  int wave = threadIdx.x >> 6, lane = threadIdx.x & 63;
  int row0 = blockIdx.x * 64 + wave * 16;
  int m = lane & 15, q = lane >> 4;
  int ybase = blockIdx.y * 10;
  f32x4 acc[10];
#pragma unroll
  for (int i = 0; i < 10; i++) acc[i] = (f32x4){0.f, 0.f, 0.f, 0.f};
  const unsigned short* arow = A + (size_t)(row0 + m) * 256 + q * 8;
  bf16x8 af[8];
#pragma unroll
  for (int k0i = 0; k0i < 8; ++k0i) af[k0i] = *(const bf16x8*)(arow + k0i * 32);
#pragma unroll
  for (int k0i = 0; k0i < 8; ++k0i) {
    const unsigned short* bk = Bp + ((size_t)k0i * NT + ybase) * 512 + lane * 8;
#pragma unroll
    for (int s = 0; s < 10; ++s) {
      bf16x8 bfr = *(const bf16x8*)(bk + s * 512);
      acc[s] = __builtin_amdgcn_mfma_f32_16x16x32_bf16(bfr, af[k0i], acc[s], 0, 0, 0);
    }
  }
  int row = row0 + m;
  if (row >= NN) return;
  int cb = q * 4;
#pragma unroll
  for (int s = 0; s < 10; ++s) {
    int nt = ybase + s;
    f32x4 v = acc[s];
    if (nt < 8) {
      int col = nt * 16 + cb;
      float4 bb = *(const float4*)(b1 + col);
      v[0] = fmaxf(v[0] + bb.x, 0.f); v[1] = fmaxf(v[1] + bb.y, 0.f);
      v[2] = fmaxf(v[2] + bb.z, 0.f); v[3] = fmaxf(v[3] + bb.w, 0.f);
      *(us4*)(h1out + (size_t)row * 256 + col) = pack4(v);
    } else if (nt < 16) {
      int col = (nt - 8) * 16 + cb;
      float4 bb = *(const float4*)(br1 + col);
      v[0] += bb.x; v[1] += bb.y; v[2] += bb.z; v[3] += bb.w;
      *(us4*)(res1 + (size_t)row * 128 + col) = pack4(v);
    } else {
      int col = (nt - 16) * 16 + cb;
      float4 bb = *(const float4*)(br2 + col);
      v[0] += bb.x; v[1] += bb.y; v[2] += bb.z; v[3] += bb.w;
      *(us4*)(res2 + (size_t)row * 64 + col) = pack4(v);
    }
  }
}

// ---------------- GEMM2/3: A[NN x 256] @ Bp -> out (+bias, +res(bf16), relu/sig8) -
// 16 rows/wave, 64 rows/block; grid.y picks 4 tiles. Swapped-operand MFMA.
template <int NTT>
__global__ __launch_bounds__(256) void gemm23_kernel(
    const unsigned short* __restrict__ A,
    const unsigned short* __restrict__ Bp,
    const float* __restrict__ bias,
    const unsigned short* __restrict__ res, int res_stride,
    unsigned short* __restrict__ out_bf,   // stride 256, may be null
    float* __restrict__ out_f, int of_stride,
    int relu, int sig8)
{
  int wave = threadIdx.x >> 6, lane = threadIdx.x & 63;
  int row0 = blockIdx.x * 64 + wave * 16;
  int m = lane & 15, q = lane >> 4;
  int ybase = blockIdx.y * 4;
  f32x4 acc[4];
#pragma unroll
  for (int i = 0; i < 4; i++) acc[i] = (f32x4){0.f, 0.f, 0.f, 0.f};
  const unsigned short* arow = A + (size_t)(row0 + m) * 256 + q * 8;
  bf16x8 af[8];
#pragma unroll
  for (int k0i = 0; k0i < 8; ++k0i) af[k0i] = *(const bf16x8*)(arow + k0i * 32);
#pragma unroll
  for (int k0i = 0; k0i < 8; ++k0i) {
    const unsigned short* bk = Bp + ((size_t)k0i * NTT + ybase) * 512 + lane * 8;
#pragma unroll
    for (int s = 0; s < 4; ++s) {
      bf16x8 bfr = *(const bf16x8*)(bk + s * 512);
      acc[s] = __builtin_amdgcn_mfma_f32_16x16x32_bf16(bfr, af[k0i], acc[s], 0, 0, 0);
    }
  }
  int row = row0 + m;
  if (row >= NN) return;
  int cb = q * 4;
#pragma unroll
  for (int s = 0; s < 4; ++s) {
    int col = (ybase + s) * 16 + cb;
    f32x4 v = acc[s];
    float4 bb = *(const float4*)(bias + col);
    v[0] += bb.x; v[1] += bb.y; v[2] += bb.z; v[3] += bb.w;
    if (relu) {
#pragma unroll
      for (int r = 0; r < 4; r++) v[r] = fmaxf(v[r], 0.f);
    }
    if (res) {
      us4 rv = *(const us4*)(res + (size_t)row * res_stride + col);
#pragma unroll
      for (int r = 0; r < 4; r++) v[r] += bf2f(rv[r]);
    }
    if (sig8 && col < 8) {
#pragma unroll
      for (int r = 0; r < 4; r++) v[r] = 1.f / (1.f + __expf(-v[r]));
    }
    if (out_bf) *(us4*)(out_bf + (size_t)row * 256 + col) = pack4(v);
    if (out_f) {
      float4 o = { v[0], v[1], v[2], v[3] };
      *(float4*)(out_f + (size_t)row * of_stride + col) = o;
    }
  }
}

extern "C" void kernel_launch(void* const* d_in, const int* in_sizes, int n_in,
                              void* d_out, int out_size, void* d_ws, size_t ws_size,
                              hipStream_t stream) {
  const float* z   = (const float*)d_in[0];
  const int*   edge = (const int*)d_in[1];
  const int*   srcn = edge;        // edge_index[0]
  const int*   dstn = edge + NE;   // edge_index[1]
  const float* w1n = (const float*)d_in[2];
  const float* w1r = (const float*)d_in[3];
  const float* b1  = (const float*)d_in[4];
  const float* w2n = (const float*)d_in[5];
  const float* w2r = (const float*)d_in[6];
  const float* b2  = (const float*)d_in[7];
  const float* wfn = (const float*)d_in[8];
  const float* wfr = (const float*)d_in[9];
  const float* bfb = (const float*)d_in[10];
  const float* wr1 = (const float*)d_in[11];
  const float* br1 = (const float*)d_in[12];
  const float* wr2 = (const float*)d_in[13];
  const float* br2 = (const float*)d_in[14];
  float* out = (float*)d_out;

  char* p = (char*)d_ws;
  auto alloc = [&](size_t bytes) { char* r = p; p += (bytes + 255) & ~255ull; return r; };
  int* deg    = (int*)alloc((size_t)NN * 4);
  int* cursor = (int*)alloc((size_t)NN * 4);
  int* rowoff = (int*)alloc((size_t)(NN + 1) * 4);
  int* partials = (int*)alloc(256 * 4);
  int* csr    = (int*)alloc((size_t)NE * 4);
  unsigned short* A1 = (unsigned short*)alloc((size_t)NN * 256 * 2);  // [mean1|z_bf], later reused as A3
  unsigned short* A2 = (unsigned short*)alloc((size_t)NN * 256 * 2);  // [mean2|h1]
  unsigned short* res1 = (unsigned short*)alloc((size_t)NN * 128 * 2);
  unsigned short* res2 = (unsigned short*)alloc((size_t)NN * 64 * 2);
  unsigned short* Bp1 = (unsigned short*)alloc(10240 * 8 * 2);
  unsigned short* Bp2 = (unsigned short*)alloc(4096 * 8 * 2);
  unsigned short* Bp3 = (unsigned short*)alloc(2048 * 8 * 2);
  unsigned short* A3 = A1;  // alias: A1 dead once gemm1 outputs land

  // zero deg + cursor (contiguous region)
  size_t zlen = (size_t)((char*)cursor - (char*)deg) + (size_t)NN * 4;
  hipMemsetAsync(deg, 0, zlen, stream);

  // CSR build
  deg_kernel<<<(NE + 255) / 256, 256, 0, stream>>>(dstn, deg);
  int nel = NN + 1;
  int nblk = (nel + 255) / 256;   // 196
  scan1_kernel<<<nblk, 256, 0, stream>>>(deg, rowoff, partials, nel, NN);
  scan2_kernel<<<1, 256, 0, stream>>>(partials, nblk);
  scan3_kernel<<<nblk, 256, 0, stream>>>(rowoff, partials, nel);
  fill_kernel<<<(NE + 255) / 256, 256, 0, stream>>>(srcn, dstn, rowoff, cursor, csr);

  // weight prep + z conversion
  prep_kernel<<<64, 256, 0, stream>>>(w1n, w1r, w2n, w2r, wfn, wfr, wr1, wr2, Bp1, Bp2, Bp3);
  convz_kernel<<<(NN * 128 / 4 + 255) / 256, 256, 0, stream>>>(z, A1);

  const int gx = (NN + 63) / 64;      // 782
  const int agg_blocks = (NN + 3) / 4;  // 12500

  // layer 1: mean1 = agg(z); fused GEMM -> h1 (A2 right), res1, res2 (bf16)
  agg_kernel<<<agg_blocks, 256, 0, stream>>>(A1 + 128, 256, A1, 256, rowoff, csr);
  gemm1_kernel<<<dim3(gx, 2), 256, 0, stream>>>(A1, Bp1, b1, br1, br2, A2 + 128, res1, res2);

  // layer 2: mean2 = agg(h1); h2 = relu([mean2|h1]@W2+b2) + res1 -> A3 right
  agg_kernel<<<agg_blocks, 256, 0, stream>>>(A2 + 128, 256, A2, 256, rowoff, csr);
  gemm23_kernel<8><<<dim3(gx, 2), 256, 0, stream>>>(A2, Bp2, b2, res1, 128,
      A3 + 128, nullptr, 0, 1, 0);

  // layer 3: mean3 = agg(h2); out = [mean3|h2]@Wf+bf + res2, sigmoid cols 0..7
  agg_kernel<<<agg_blocks, 256, 0, stream>>>(A3 + 128, 256, A3, 256, rowoff, csr);
  gemm23_kernel<4><<<dim3(gx, 1), 256, 0, stream>>>(A3, Bp3, bfb, res2, 64,
      nullptr, out, 64, 0, 1);
}

// Round 6
// 308.577 us; speedup vs baseline: 1.8675x; 1.1659x over previous
//
#include <hip/hip_runtime.h>
#include <hip/hip_bf16.h>
#include <math.h>

#define NN 50000
#define NE 800000
#define NB 391          // buckets of 128 nodes: ceil(50000/128)
#define EPB 6250        // edges per bscat/bhist block (128 blocks)

typedef short bf16x8 __attribute__((ext_vector_type(8)));
typedef float f32x4 __attribute__((ext_vector_type(4)));
typedef unsigned short us4 __attribute__((ext_vector_type(4)));
typedef unsigned short us8 __attribute__((ext_vector_type(8)));
typedef unsigned int u32x4 __attribute__((ext_vector_type(4)));

__device__ __forceinline__ float bf2f(unsigned short u) {
  union { unsigned int i; float f; } x; x.i = ((unsigned int)u) << 16; return x.f;
}
__device__ __forceinline__ unsigned short f2bf(float f) {
  union { float f; unsigned int i; } x; x.f = f;
  unsigned int i = x.i;
  unsigned int r = i + 0x7FFF + ((i >> 16) & 1);   // round-to-nearest-even
  return (unsigned short)(r >> 16);
}
__device__ __forceinline__ us4 pack4(f32x4 v) {
  us4 o; o[0] = f2bf(v[0]); o[1] = f2bf(v[1]); o[2] = f2bf(v[2]); o[3] = f2bf(v[3]);
  return o;
}

// ---------------- CSR build, bucketed (all random scatter kept in LDS) --------
// Stage 1: global bucket histogram (bucket = dst >> 7)
__global__ __launch_bounds__(256) void bhist_kernel(const int* __restrict__ dstn,
                                                    int* __restrict__ bhist) {
  __shared__ int h[NB];
  for (int i = threadIdx.x; i < NB; i += 256) h[i] = 0;
  __syncthreads();
  int e0 = blockIdx.x * EPB;
  for (int i = threadIdx.x; i < EPB; i += 256)
    atomicAdd(&h[dstn[e0 + i] >> 7], 1);
  __syncthreads();
  for (int i = threadIdx.x; i < NB; i += 256)
    if (h[i]) atomicAdd(&bhist[i], h[i]);
}

// Stage 2: exclusive scan of bucket counts -> bucket_off; zero gcur
__global__ __launch_bounds__(512) void bscan_kernel(const int* __restrict__ bhist,
                                                    int* __restrict__ bucket_off,
                                                    int* __restrict__ gcur) {
  __shared__ int s[512];
  int t = threadIdx.x;
  int v = (t < NB) ? bhist[t] : 0;
  s[t] = v; __syncthreads();
  for (int off = 1; off < 512; off <<= 1) {
    int x = (t >= off) ? s[t - off] : 0;
    __syncthreads();
    s[t] += x;
    __syncthreads();
  }
  if (t < NB) { bucket_off[t] = s[t] - v; gcur[t] = 0; }
  if (t == NB - 1) bucket_off[NB] = s[t];
}

// Stage 3: scatter (src,dst) into bucket-grouped ebuf. Each block reserves one
// contiguous slice per bucket -> its writes stay in ~128B regions owned by one
// XCD -> full-line writebacks, no cross-XCD line bouncing.
__global__ __launch_bounds__(256) void bscat_kernel(const int* __restrict__ srcn,
                                                    const int* __restrict__ dstn,
                                                    const int* __restrict__ bucket_off,
                                                    int* __restrict__ gcur,
                                                    unsigned long long* __restrict__ ebuf) {
  __shared__ int hist[NB];
  __shared__ int base[NB];
  for (int i = threadIdx.x; i < NB; i += 256) hist[i] = 0;
  __syncthreads();
  int e0 = blockIdx.x * EPB;
  for (int i = threadIdx.x; i < EPB; i += 256)
    atomicAdd(&hist[dstn[e0 + i] >> 7], 1);
  __syncthreads();
  for (int i = threadIdx.x; i < NB; i += 256) {
    int c = hist[i];
    base[i] = c ? (bucket_off[i] + atomicAdd(&gcur[i], c)) : 0;
  }
  __syncthreads();
  for (int i = threadIdx.x; i < EPB; i += 256) {
    int s = srcn[e0 + i], d = dstn[e0 + i];
    int b = d >> 7;
    int pos = atomicSub(&hist[b], 1) - 1;   // order within slice irrelevant
    ebuf[(size_t)base[b] + pos] = ((unsigned long long)(unsigned)d << 32) | (unsigned)s;
  }
}

// Stage 4: per bucket: node degrees (LDS), local scan -> rowoff, scatter src
// into the bucket's contiguous csr region (LDS atomics only).
__global__ __launch_bounds__(256) void bfill_kernel(const unsigned long long* __restrict__ ebuf,
                                                    const int* __restrict__ bucket_off,
                                                    int* __restrict__ rowoff,
                                                    int* __restrict__ csr) {
  int b = blockIdx.x;
  int bo = bucket_off[b], cnt = bucket_off[b + 1] - bo;
  __shared__ int ndeg[128], noff[128];
  int t = threadIdx.x;
  if (t < 128) ndeg[t] = 0;
  __syncthreads();
  for (int i = t; i < cnt; i += 256)
    atomicAdd(&ndeg[(int)(ebuf[bo + i] >> 32) & 127], 1);
  __syncthreads();
  if (t < 128) noff[t] = ndeg[t];
  __syncthreads();
  for (int off = 1; off < 128; off <<= 1) {   // inclusive scan (Hillis-Steele)
    int x = 0;
    if (t < 128 && t >= off) x = noff[t - off];
    __syncthreads();
    if (t < 128 && t >= off) noff[t] += x;
    __syncthreads();
  }
  if (t < 128) {
    int ex = noff[t] - ndeg[t];    // exclusive
    noff[t] = ex;
    int node = b * 128 + t;
    if (node < NN) rowoff[node] = bo + ex;
  }
  if (b == NB - 1 && t == 0) rowoff[NN] = NE;
  __syncthreads();
  for (int i = t; i < cnt; i += 256) {
    unsigned long long e = ebuf[bo + i];
    int dl = (int)(e >> 32) & 127;
    int pos = atomicSub(&ndeg[dl], 1) - 1;
    csr[bo + noff[dl] + pos] = (int)(unsigned)e;
  }
}

// ---------------- weight prep: pack B into MFMA fragment-major layout ----------
// frag index fi = (k0i*NT + nt)*64 + lane; 8 bf16 per frag at Bp+fi*8.
// Lane (m=lane&15, q=lane>>4) holds W[k][n], k = k0i*32+q*8+j, n = nt*16+m.
// Bp1 = [w1n;w1r | 0;wr1 | 0;wr2], N=320 (NT=20), K=256.
// Bp2 = [w2n;w2r] (NT=8).  Bp3 = [wfn;wfr] (NT=4).
__global__ void prep_kernel(const float* __restrict__ w1n, const float* __restrict__ w1r,
                            const float* __restrict__ w2n, const float* __restrict__ w2r,
                            const float* __restrict__ wfn, const float* __restrict__ wfr,
                            const float* __restrict__ wr1, const float* __restrict__ wr2,
                            unsigned short* __restrict__ Bp1, unsigned short* __restrict__ Bp2,
                            unsigned short* __restrict__ Bp3) {
  int g = blockIdx.x * 256 + threadIdx.x;
  unsigned short* D; int NT, fi;
  int which;  // 1,2,3
  if      (g < 10240) { fi = g;         D = Bp1; NT = 20; which = 1; }
  else if (g < 14336) { fi = g - 10240; D = Bp2; NT = 8;  which = 2; }
  else if (g < 16384) { fi = g - 14336; D = Bp3; NT = 4;  which = 3; }
  else return;
  int lane = fi & 63, t = fi >> 6;
  int nt = t % NT, k0i = t / NT;
  int m = lane & 15, q = lane >> 4;
  int kb = k0i * 32 + q * 8;          // 8-aligned: all j on same side of 128
  int n = nt * 16 + m;
  int hi = (kb >= 128);
  int k0_ = kb - (hi ? 128 : 0);
  const float* W = nullptr; int Nseg = 128; int nn = n;
  if (which == 1) {
    if (n < 128)      { W = hi ? w1r : w1n; nn = n; Nseg = 128; }
    else if (n < 256) { W = hi ? wr1 : nullptr; nn = n - 128; Nseg = 128; }
    else              { W = hi ? wr2 : nullptr; nn = n - 256; Nseg = 64; }
  } else if (which == 2) { W = hi ? w2r : w2n; Nseg = 128; }
  else                   { W = hi ? wfr : wfn; Nseg = 64; }
  unsigned short o[8];
#pragma unroll
  for (int j = 0; j < 8; j++)
    o[j] = W ? f2bf(W[(size_t)(k0_ + j) * Nseg + nn]) : (unsigned short)0;
  *(us8*)(D + (size_t)fi * 8) = *(const us8*)o;
}

// ---------------- z (f32) -> bf16 into A1 right half ----------------
__global__ void convz_kernel(const float* __restrict__ z, unsigned short* __restrict__ A1) {
  int i = blockIdx.x * 256 + threadIdx.x;   // groups of 4 elements
  if (i >= NN * 128 / 4) return;
  int i4 = i * 4;
  int row = i4 >> 7, c = i4 & 127;
  float4 v = *(const float4*)(z + i4);
  us4 o = { f2bf(v.x), f2bf(v.y), f2bf(v.z), f2bf(v.w) };
  *(us4*)(A1 + (size_t)row * 256 + 128 + c) = o;
}

// ---------------- mean aggregation: one wave per node, 4 subgroups x 4-deep MLP --
__global__ __launch_bounds__(256) void agg_kernel(const unsigned short* __restrict__ feat, int fstride,
                                                  unsigned short* __restrict__ outm, int ostride,
                                                  const int* __restrict__ rowoff,
                                                  const int* __restrict__ csr) {
  int wave = threadIdx.x >> 6, lane = threadIdx.x & 63;
  int node = blockIdx.x * 4 + wave;
  if (node >= NN) return;
  int beg = rowoff[node], end = rowoff[node + 1];
  int g = lane >> 4;           // neighbor subgroup 0..3
  int c = (lane & 15) << 3;    // column offset (8 bf16 = 16B per lane)
  float a[8];
#pragma unroll
  for (int i = 0; i < 8; i++) a[i] = 0.f;
  int j = beg + g;
  for (; j + 12 < end; j += 16) {   // 4 row-reads in flight per subgroup
    int s0 = csr[j];
    int s1 = csr[j + 4];
    int s2 = csr[j + 8];
    int s3 = csr[j + 12];
    u32x4 v0 = *(const u32x4*)(feat + (size_t)s0 * fstride + c);
    u32x4 v1 = *(const u32x4*)(feat + (size_t)s1 * fstride + c);
    u32x4 v2 = *(const u32x4*)(feat + (size_t)s2 * fstride + c);
    u32x4 v3 = *(const u32x4*)(feat + (size_t)s3 * fstride + c);
#pragma unroll
    for (int i = 0; i < 4; i++) {
      a[2*i]   += bf2f((unsigned short)(v0[i] & 0xffff)) + bf2f((unsigned short)(v1[i] & 0xffff))
                + bf2f((unsigned short)(v2[i] & 0xffff)) + bf2f((unsigned short)(v3[i] & 0xffff));
      a[2*i+1] += bf2f((unsigned short)(v0[i] >> 16)) + bf2f((unsigned short)(v1[i] >> 16))
                + bf2f((unsigned short)(v2[i] >> 16)) + bf2f((unsigned short)(v3[i] >> 16));
    }
  }
  for (; j < end; j += 4) {
    int s0 = csr[j];
    u32x4 v0 = *(const u32x4*)(feat + (size_t)s0 * fstride + c);
#pragma unroll
    for (int i = 0; i < 4; i++) {
      a[2*i]   += bf2f((unsigned short)(v0[i] & 0xffff));
      a[2*i+1] += bf2f((unsigned short)(v0[i] >> 16));
    }
  }
#pragma unroll
  for (int i = 0; i < 8; i++) {
    a[i] += __shfl_xor(a[i], 16, 64);
    a[i] += __shfl_xor(a[i], 32, 64);
  }
  if (g == 0) {
    float inv = 1.f / fmaxf((float)(end - beg), 1.f);
    unsigned int o[4];
#pragma unroll
    for (int i = 0; i < 4; i++)
      o[i] = ((unsigned int)f2bf(a[2*i+1] * inv) << 16) | f2bf(a[2*i] * inv);
    *(u32x4*)(outm + (size_t)node * ostride + c) = *(const u32x4*)o;
  }
}

// ---------------- GEMM1: A1[NN x 256] @ Bp1(NT=20) -> h1 | res1 | res2 ----------
// grid (782, 2): y picks 10 tiles. Swapped-operand MFMA: acc holds C^T, so each
// lane has row = lane&15, cols q*4+reg -> packed 8B bf16 stores.
__global__ __launch_bounds__(256) void gemm1_kernel(
    const unsigned short* __restrict__ A,
    const unsigned short* __restrict__ Bp,
    const float* __restrict__ b1, const float* __restrict__ br1, const float* __restrict__ br2,
    unsigned short* __restrict__ h1out,   // A2+128, stride 256
    unsigned short* __restrict__ res1, unsigned short* __restrict__ res2)
{
  const int NT = 20;
  int wave = threadIdx.x >> 6, lane = threadIdx.x & 63;
  int row0 = blockIdx.x * 64 + wave * 16;
  int m = lane & 15, q = lane >> 4;
  int ybase = blockIdx.y * 10;
  f32x4 acc[10];
#pragma unroll
  for (int i = 0; i < 10; i++) acc[i] = (f32x4){0.f, 0.f, 0.f, 0.f};
  const unsigned short* arow = A + (size_t)(row0 + m) * 256 + q * 8;
  bf16x8 af[8];
#pragma unroll
  for (int k0i = 0; k0i < 8; ++k0i) af[k0i] = *(const bf16x8*)(arow + k0i * 32);
#pragma unroll
  for (int k0i = 0; k0i < 8; ++k0i) {
    const unsigned short* bk = Bp + ((size_t)k0i * NT + ybase) * 512 + lane * 8;
#pragma unroll
    for (int s = 0; s < 10; ++s) {
      bf16x8 bfr = *(const bf16x8*)(bk + s * 512);
      acc[s] = __builtin_amdgcn_mfma_f32_16x16x32_bf16(bfr, af[k0i], acc[s], 0, 0, 0);
    }
  }
  int row = row0 + m;
  if (row >= NN) return;
  int cb = q * 4;
#pragma unroll
  for (int s = 0; s < 10; ++s) {
    int nt = ybase + s;
    f32x4 v = acc[s];
    if (nt < 8) {
      int col = nt * 16 + cb;
      float4 bb = *(const float4*)(b1 + col);
      v[0] = fmaxf(v[0] + bb.x, 0.f); v[1] = fmaxf(v[1] + bb.y, 0.f);
      v[2] = fmaxf(v[2] + bb.z, 0.f); v[3] = fmaxf(v[3] + bb.w, 0.f);
      *(us4*)(h1out + (size_t)row * 256 + col) = pack4(v);
    } else if (nt < 16) {
      int col = (nt - 8) * 16 + cb;
      float4 bb = *(const float4*)(br1 + col);
      v[0] += bb.x; v[1] += bb.y; v[2] += bb.z; v[3] += bb.w;
      *(us4*)(res1 + (size_t)row * 128 + col) = pack4(v);
    } else {
      int col = (nt - 16) * 16 + cb;
      float4 bb = *(const float4*)(br2 + col);
      v[0] += bb.x; v[1] += bb.y; v[2] += bb.z; v[3] += bb.w;
      *(us4*)(res2 + (size_t)row * 64 + col) = pack4(v);
    }
  }
}

// ---------------- GEMM2/3: A[NN x 256] @ Bp -> out (+bias, +res(bf16), relu/sig8) -
// 16 rows/wave, 64 rows/block; grid.y picks 4 tiles. Swapped-operand MFMA.
template <int NTT>
__global__ __launch_bounds__(256) void gemm23_kernel(
    const unsigned short* __restrict__ A,
    const unsigned short* __restrict__ Bp,
    const float* __restrict__ bias,
    const unsigned short* __restrict__ res, int res_stride,
    unsigned short* __restrict__ out_bf,   // stride 256, may be null
    float* __restrict__ out_f, int of_stride,
    int relu, int sig8)
{
  int wave = threadIdx.x >> 6, lane = threadIdx.x & 63;
  int row0 = blockIdx.x * 64 + wave * 16;
  int m = lane & 15, q = lane >> 4;
  int ybase = blockIdx.y * 4;
  f32x4 acc[4];
#pragma unroll
  for (int i = 0; i < 4; i++) acc[i] = (f32x4){0.f, 0.f, 0.f, 0.f};
  const unsigned short* arow = A + (size_t)(row0 + m) * 256 + q * 8;
  bf16x8 af[8];
#pragma unroll
  for (int k0i = 0; k0i < 8; ++k0i) af[k0i] = *(const bf16x8*)(arow + k0i * 32);
#pragma unroll
  for (int k0i = 0; k0i < 8; ++k0i) {
    const unsigned short* bk = Bp + ((size_t)k0i * NTT + ybase) * 512 + lane * 8;
#pragma unroll
    for (int s = 0; s < 4; ++s) {
      bf16x8 bfr = *(const bf16x8*)(bk + s * 512);
      acc[s] = __builtin_amdgcn_mfma_f32_16x16x32_bf16(bfr, af[k0i], acc[s], 0, 0, 0);
    }
  }
  int row = row0 + m;
  if (row >= NN) return;
  int cb = q * 4;
#pragma unroll
  for (int s = 0; s < 4; ++s) {
    int col = (ybase + s) * 16 + cb;
    f32x4 v = acc[s];
    float4 bb = *(const float4*)(bias + col);
    v[0] += bb.x; v[1] += bb.y; v[2] += bb.z; v[3] += bb.w;
    if (relu) {
#pragma unroll
      for (int r = 0; r < 4; r++) v[r] = fmaxf(v[r], 0.f);
    }
    if (res) {
      us4 rv = *(const us4*)(res + (size_t)row * res_stride + col);
#pragma unroll
      for (int r = 0; r < 4; r++) v[r] += bf2f(rv[r]);
    }
    if (sig8 && col < 8) {
#pragma unroll
      for (int r = 0; r < 4; r++) v[r] = 1.f / (1.f + __expf(-v[r]));
    }
    if (out_bf) *(us4*)(out_bf + (size_t)row * 256 + col) = pack4(v);
    if (out_f) {
      float4 o = { v[0], v[1], v[2], v[3] };
      *(float4*)(out_f + (size_t)row * of_stride + col) = o;
    }
  }
}

extern "C" void kernel_launch(void* const* d_in, const int* in_sizes, int n_in,
                              void* d_out, int out_size, void* d_ws, size_t ws_size,
                              hipStream_t stream) {
  const float* z   = (const float*)d_in[0];
  const int*   edge = (const int*)d_in[1];
  const int*   srcn = edge;        // edge_index[0]
  const int*   dstn = edge + NE;   // edge_index[1]
  const float* w1n = (const float*)d_in[2];
  const float* w1r = (const float*)d_in[3];
  const float* b1  = (const float*)d_in[4];
  const float* w2n = (const float*)d_in[5];
  const float* w2r = (const float*)d_in[6];
  const float* b2  = (const float*)d_in[7];
  const float* wfn = (const float*)d_in[8];
  const float* wfr = (const float*)d_in[9];
  const float* bfb = (const float*)d_in[10];
  const float* wr1 = (const float*)d_in[11];
  const float* br1 = (const float*)d_in[12];
  const float* wr2 = (const float*)d_in[13];
  const float* br2 = (const float*)d_in[14];
  float* out = (float*)d_out;

  char* p = (char*)d_ws;
  auto alloc = [&](size_t bytes) { char* r = p; p += (bytes + 255) & ~255ull; return r; };
  int* rowoff = (int*)alloc((size_t)(NN + 1) * 4);
  int* bhist  = (int*)alloc((size_t)NB * 4);
  int* bucket_off = (int*)alloc((size_t)(NB + 1) * 4);
  int* gcur   = (int*)alloc((size_t)NB * 4);
  int* csr    = (int*)alloc((size_t)NE * 4);
  unsigned short* A1 = (unsigned short*)alloc((size_t)NN * 256 * 2);  // [mean1|z_bf], later reused as A3
  unsigned short* A2 = (unsigned short*)alloc((size_t)NN * 256 * 2);  // [mean2|h1]
  unsigned short* res1 = (unsigned short*)alloc((size_t)NN * 128 * 2);
  unsigned short* res2 = (unsigned short*)alloc((size_t)NN * 64 * 2);
  unsigned short* Bp1 = (unsigned short*)alloc(10240 * 8 * 2);
  unsigned short* Bp2 = (unsigned short*)alloc(4096 * 8 * 2);
  unsigned short* Bp3 = (unsigned short*)alloc(2048 * 8 * 2);
  unsigned short* A3 = A1;  // alias: A1 dead once gemm1 outputs land
  // ebuf aliases res1 (6.4 MB <= 12.8 MB): dead before gemm1 writes res1
  unsigned long long* ebuf = (unsigned long long*)res1;

  // CSR build (bucketed counting sort; only bhist needs pre-zero)
  hipMemsetAsync(bhist, 0, (size_t)NB * 4, stream);
  bhist_kernel<<<128, 256, 0, stream>>>(dstn, bhist);
  bscan_kernel<<<1, 512, 0, stream>>>(bhist, bucket_off, gcur);
  bscat_kernel<<<128, 256, 0, stream>>>(srcn, dstn, bucket_off, gcur, ebuf);
  bfill_kernel<<<NB, 256, 0, stream>>>(ebuf, bucket_off, rowoff, csr);

  // weight prep + z conversion
  prep_kernel<<<64, 256, 0, stream>>>(w1n, w1r, w2n, w2r, wfn, wfr, wr1, wr2, Bp1, Bp2, Bp3);
  convz_kernel<<<(NN * 128 / 4 + 255) / 256, 256, 0, stream>>>(z, A1);

  const int gx = (NN + 63) / 64;      // 782
  const int agg_blocks = (NN + 3) / 4;  // 12500

  // layer 1: mean1 = agg(z); fused GEMM -> h1 (A2 right), res1, res2 (bf16)
  agg_kernel<<<agg_blocks, 256, 0, stream>>>(A1 + 128, 256, A1, 256, rowoff, csr);
  gemm1_kernel<<<dim3(gx, 2), 256, 0, stream>>>(A1, Bp1, b1, br1, br2, A2 + 128, res1, res2);

  // layer 2: mean2 = agg(h1); h2 = relu([mean2|h1]@W2+b2) + res1 -> A3 right
  agg_kernel<<<agg_blocks, 256, 0, stream>>>(A2 + 128, 256, A2, 256, rowoff, csr);
  gemm23_kernel<8><<<dim3(gx, 2), 256, 0, stream>>>(A2, Bp2, b2, res1, 128,
      A3 + 128, nullptr, 0, 1, 0);

  // layer 3: mean3 = agg(h2); out = [mean3|h2]@Wf+bf + res2, sigmoid cols 0..7
  agg_kernel<<<agg_blocks, 256, 0, stream>>>(A3 + 128, 256, A3, 256, rowoff, csr);
  gemm23_kernel<4><<<dim3(gx, 1), 256, 0, stream>>>(A3, Bp3, bfb, res2, 64,
      nullptr, out, 64, 0, 1);
}

// Round 7
// 297.603 us; speedup vs baseline: 1.9363x; 1.0369x over previous
//
#include <hip/hip_runtime.h>
#include <hip/hip_bf16.h>
#include <math.h>

#define NN 50000
#define NE 800000
#define NB 391          // buckets of 128 nodes: ceil(50000/128)
#define EPB 6250        // edges per bscat/bhist block (128 blocks)

typedef short bf16x8 __attribute__((ext_vector_type(8)));
typedef float f32x4 __attribute__((ext_vector_type(4)));
typedef unsigned short us4 __attribute__((ext_vector_type(4)));
typedef unsigned short us8 __attribute__((ext_vector_type(8)));
typedef unsigned int u32x4 __attribute__((ext_vector_type(4)));

__device__ __forceinline__ float bf2f(unsigned short u) {
  union { unsigned int i; float f; } x; x.i = ((unsigned int)u) << 16; return x.f;
}
__device__ __forceinline__ unsigned short f2bf(float f) {
  union { float f; unsigned int i; } x; x.f = f;
  unsigned int i = x.i;
  unsigned int r = i + 0x7FFF + ((i >> 16) & 1);   // round-to-nearest-even
  return (unsigned short)(r >> 16);
}
__device__ __forceinline__ us4 pack4(f32x4 v) {
  us4 o; o[0] = f2bf(v[0]); o[1] = f2bf(v[1]); o[2] = f2bf(v[2]); o[3] = f2bf(v[3]);
  return o;
}

// ---------------- CSR build, bucketed (all random scatter kept in LDS) --------
__global__ __launch_bounds__(256) void bhist_kernel(const int* __restrict__ dstn,
                                                    int* __restrict__ bhist) {
  __shared__ int h[NB];
  for (int i = threadIdx.x; i < NB; i += 256) h[i] = 0;
  __syncthreads();
  int e0 = blockIdx.x * EPB;
  for (int i = threadIdx.x; i < EPB; i += 256)
    atomicAdd(&h[dstn[e0 + i] >> 7], 1);
  __syncthreads();
  for (int i = threadIdx.x; i < NB; i += 256)
    if (h[i]) atomicAdd(&bhist[i], h[i]);
}

__global__ __launch_bounds__(512) void bscan_kernel(const int* __restrict__ bhist,
                                                    int* __restrict__ bucket_off,
                                                    int* __restrict__ gcur) {
  __shared__ int s[512];
  int t = threadIdx.x;
  int v = (t < NB) ? bhist[t] : 0;
  s[t] = v; __syncthreads();
  for (int off = 1; off < 512; off <<= 1) {
    int x = (t >= off) ? s[t - off] : 0;
    __syncthreads();
    s[t] += x;
    __syncthreads();
  }
  if (t < NB) { bucket_off[t] = s[t] - v; gcur[t] = 0; }
  if (t == NB - 1) bucket_off[NB] = s[t];
}

__global__ __launch_bounds__(256) void bscat_kernel(const int* __restrict__ srcn,
                                                    const int* __restrict__ dstn,
                                                    const int* __restrict__ bucket_off,
                                                    int* __restrict__ gcur,
                                                    unsigned long long* __restrict__ ebuf) {
  __shared__ int hist[NB];
  __shared__ int base[NB];
  for (int i = threadIdx.x; i < NB; i += 256) hist[i] = 0;
  __syncthreads();
  int e0 = blockIdx.x * EPB;
  for (int i = threadIdx.x; i < EPB; i += 256)
    atomicAdd(&hist[dstn[e0 + i] >> 7], 1);
  __syncthreads();
  for (int i = threadIdx.x; i < NB; i += 256) {
    int c = hist[i];
    base[i] = c ? (bucket_off[i] + atomicAdd(&gcur[i], c)) : 0;
  }
  __syncthreads();
  for (int i = threadIdx.x; i < EPB; i += 256) {
    int s = srcn[e0 + i], d = dstn[e0 + i];
    int b = d >> 7;
    int pos = atomicSub(&hist[b], 1) - 1;   // order within slice irrelevant
    ebuf[(size_t)base[b] + pos] = ((unsigned long long)(unsigned)d << 32) | (unsigned)s;
  }
}

__global__ __launch_bounds__(256) void bfill_kernel(const unsigned long long* __restrict__ ebuf,
                                                    const int* __restrict__ bucket_off,
                                                    int* __restrict__ rowoff,
                                                    int* __restrict__ csr) {
  int b = blockIdx.x;
  int bo = bucket_off[b], cnt = bucket_off[b + 1] - bo;
  __shared__ int ndeg[128], noff[128];
  int t = threadIdx.x;
  if (t < 128) ndeg[t] = 0;
  __syncthreads();
  for (int i = t; i < cnt; i += 256)
    atomicAdd(&ndeg[(int)(ebuf[bo + i] >> 32) & 127], 1);
  __syncthreads();
  if (t < 128) noff[t] = ndeg[t];
  __syncthreads();
  for (int off = 1; off < 128; off <<= 1) {   // inclusive scan (Hillis-Steele)
    int x = 0;
    if (t < 128 && t >= off) x = noff[t - off];
    __syncthreads();
    if (t < 128 && t >= off) noff[t] += x;
    __syncthreads();
  }
  if (t < 128) {
    int ex = noff[t] - ndeg[t];    // exclusive
    noff[t] = ex;
    int node = b * 128 + t;
    if (node < NN) rowoff[node] = bo + ex;
  }
  if (b == NB - 1 && t == 0) rowoff[NN] = NE;
  __syncthreads();
  for (int i = t; i < cnt; i += 256) {
    unsigned long long e = ebuf[bo + i];
    int dl = (int)(e >> 32) & 127;
    int pos = atomicSub(&ndeg[dl], 1) - 1;
    csr[bo + noff[dl] + pos] = (int)(unsigned)e;
  }
}

// ---------------- weight prep: pack B into MFMA fragment-major layout ----------
// frag index fi = (k0i*NT + nt)*64 + lane; 8 bf16 per frag at Bp+fi*8.
// Lane (m=lane&15, q=lane>>4) holds W[k][n], k = k0i*32+q*8+j, n = nt*16+m.
// Bp1 = [w1n;w1r | 0;wr1 | 0;wr2], N=320 (NT=20), K=256.
// Bp2 = [w2n;w2r] (NT=8).  Bp3 = [wfn;wfr] (NT=4).
__global__ void prep_kernel(const float* __restrict__ w1n, const float* __restrict__ w1r,
                            const float* __restrict__ w2n, const float* __restrict__ w2r,
                            const float* __restrict__ wfn, const float* __restrict__ wfr,
                            const float* __restrict__ wr1, const float* __restrict__ wr2,
                            unsigned short* __restrict__ Bp1, unsigned short* __restrict__ Bp2,
                            unsigned short* __restrict__ Bp3) {
  int g = blockIdx.x * 256 + threadIdx.x;
  unsigned short* D; int NT, fi;
  int which;  // 1,2,3
  if      (g < 10240) { fi = g;         D = Bp1; NT = 20; which = 1; }
  else if (g < 14336) { fi = g - 10240; D = Bp2; NT = 8;  which = 2; }
  else if (g < 16384) { fi = g - 14336; D = Bp3; NT = 4;  which = 3; }
  else return;
  int lane = fi & 63, t = fi >> 6;
  int nt = t % NT, k0i = t / NT;
  int m = lane & 15, q = lane >> 4;
  int kb = k0i * 32 + q * 8;          // 8-aligned: all j on same side of 128
  int n = nt * 16 + m;
  int hi = (kb >= 128);
  int k0_ = kb - (hi ? 128 : 0);
  const float* W = nullptr; int Nseg = 128; int nn = n;
  if (which == 1) {
    if (n < 128)      { W = hi ? w1r : w1n; nn = n; Nseg = 128; }
    else if (n < 256) { W = hi ? wr1 : nullptr; nn = n - 128; Nseg = 128; }
    else              { W = hi ? wr2 : nullptr; nn = n - 256; Nseg = 64; }
  } else if (which == 2) { W = hi ? w2r : w2n; Nseg = 128; }
  else                   { W = hi ? wfr : wfn; Nseg = 64; }
  unsigned short o[8];
#pragma unroll
  for (int j = 0; j < 8; j++)
    o[j] = W ? f2bf(W[(size_t)(k0_ + j) * Nseg + nn]) : (unsigned short)0;
  *(us8*)(D + (size_t)fi * 8) = *(const us8*)o;
}

// ---------------- z (f32) -> bf16 into A1 right half ----------------
__global__ void convz_kernel(const float* __restrict__ z, unsigned short* __restrict__ A1) {
  int i = blockIdx.x * 256 + threadIdx.x;   // groups of 4 elements
  if (i >= NN * 128 / 4) return;
  int i4 = i * 4;
  int row = i4 >> 7, c = i4 & 127;
  float4 v = *(const float4*)(z + i4);
  us4 o = { f2bf(v.x), f2bf(v.y), f2bf(v.z), f2bf(v.w) };
  *(us4*)(A1 + (size_t)row * 256 + 128 + c) = o;
}

// ---------------- mean aggregation: one wave per node, 4 subgroups x 4-deep MLP --
__global__ __launch_bounds__(256) void agg_kernel(const unsigned short* __restrict__ feat, int fstride,
                                                  unsigned short* __restrict__ outm, int ostride,
                                                  const int* __restrict__ rowoff,
                                                  const int* __restrict__ csr) {
  int wave = threadIdx.x >> 6, lane = threadIdx.x & 63;
  int node = blockIdx.x * 4 + wave;
  if (node >= NN) return;
  int beg = rowoff[node], end = rowoff[node + 1];
  int g = lane >> 4;           // neighbor subgroup 0..3
  int c = (lane & 15) << 3;    // column offset (8 bf16 = 16B per lane)
  float a[8];
#pragma unroll
  for (int i = 0; i < 8; i++) a[i] = 0.f;
  int j = beg + g;
  for (; j + 12 < end; j += 16) {   // 4 row-reads in flight per subgroup
    int s0 = csr[j];
    int s1 = csr[j + 4];
    int s2 = csr[j + 8];
    int s3 = csr[j + 12];
    u32x4 v0 = *(const u32x4*)(feat + (size_t)s0 * fstride + c);
    u32x4 v1 = *(const u32x4*)(feat + (size_t)s1 * fstride + c);
    u32x4 v2 = *(const u32x4*)(feat + (size_t)s2 * fstride + c);
    u32x4 v3 = *(const u32x4*)(feat + (size_t)s3 * fstride + c);
#pragma unroll
    for (int i = 0; i < 4; i++) {
      a[2*i]   += bf2f((unsigned short)(v0[i] & 0xffff)) + bf2f((unsigned short)(v1[i] & 0xffff))
                + bf2f((unsigned short)(v2[i] & 0xffff)) + bf2f((unsigned short)(v3[i] & 0xffff));
      a[2*i+1] += bf2f((unsigned short)(v0[i] >> 16)) + bf2f((unsigned short)(v1[i] >> 16))
                + bf2f((unsigned short)(v2[i] >> 16)) + bf2f((unsigned short)(v3[i] >> 16));
    }
  }
  for (; j < end; j += 4) {
    int s0 = csr[j];
    u32x4 v0 = *(const u32x4*)(feat + (size_t)s0 * fstride + c);
#pragma unroll
    for (int i = 0; i < 4; i++) {
      a[2*i]   += bf2f((unsigned short)(v0[i] & 0xffff));
      a[2*i+1] += bf2f((unsigned short)(v0[i] >> 16));
    }
  }
#pragma unroll
  for (int i = 0; i < 8; i++) {
    a[i] += __shfl_xor(a[i], 16, 64);
    a[i] += __shfl_xor(a[i], 32, 64);
  }
  if (g == 0) {
    float inv = 1.f / fmaxf((float)(end - beg), 1.f);
    unsigned int o[4];
#pragma unroll
    for (int i = 0; i < 4; i++)
      o[i] = ((unsigned int)f2bf(a[2*i+1] * inv) << 16) | f2bf(a[2*i] * inv);
    *(u32x4*)(outm + (size_t)node * ostride + c) = *(const u32x4*)o;
  }
}

// ---------------- GEMM1: A1[NN x 256] @ Bp1(NT=20) -> h1 | res1 | res2 ----------
// grid (4, 782): x = tile-group (fastest-varying in dispatch order so consecutive
// blocks share A rows via L2), y = row block. B-panel (5 tiles x 8 k-steps = 40 KB)
// staged once into LDS -> K-loop reads are ds_read_b128, no global latency chain.
__global__ __launch_bounds__(256) void gemm1_kernel(
    const unsigned short* __restrict__ A,
    const unsigned short* __restrict__ Bp,
    const float* __restrict__ b1, const float* __restrict__ br1, const float* __restrict__ br2,
    unsigned short* __restrict__ h1out,   // A2+128, stride 256
    unsigned short* __restrict__ res1, unsigned short* __restrict__ res2)
{
  const int NT = 20, TILES = 5;
  __shared__ unsigned short Bs[TILES * 8 * 512];   // 40 KB
  int tid = threadIdx.x;
  int wave = tid >> 6, lane = tid & 63;
  int ybase = blockIdx.x * TILES;
  // stage B panel: per k0i a contiguous TILES*1KB run of Bp
#pragma unroll
  for (int i = tid; i < TILES * 64 * 8; i += 256) {     // us8 copies
    int k0i = i / (TILES * 64), r = i % (TILES * 64);
    *(us8*)(Bs + (size_t)k0i * TILES * 512 + (size_t)r * 8) =
        *(const us8*)(Bp + ((size_t)k0i * NT + ybase) * 512 + (size_t)r * 8);
  }
  int row0 = blockIdx.y * 64 + wave * 16;
  int m = lane & 15, q = lane >> 4;
  const unsigned short* arow = A + (size_t)(row0 + m) * 256 + q * 8;
  bf16x8 af[8];
#pragma unroll
  for (int k0i = 0; k0i < 8; ++k0i) af[k0i] = *(const bf16x8*)(arow + k0i * 32);
  __syncthreads();
  f32x4 acc[TILES];
#pragma unroll
  for (int i = 0; i < TILES; i++) acc[i] = (f32x4){0.f, 0.f, 0.f, 0.f};
#pragma unroll
  for (int k0i = 0; k0i < 8; ++k0i) {
    const unsigned short* bk = Bs + (size_t)k0i * TILES * 512 + lane * 8;
#pragma unroll
    for (int s = 0; s < TILES; ++s) {
      bf16x8 bfr = *(const bf16x8*)(bk + s * 512);
      acc[s] = __builtin_amdgcn_mfma_f32_16x16x32_bf16(bfr, af[k0i], acc[s], 0, 0, 0);
    }
  }
  int row = row0 + m;
  if (row >= NN) return;
  int cb = q * 4;
#pragma unroll
  for (int s = 0; s < TILES; ++s) {
    int nt = ybase + s;
    f32x4 v = acc[s];
    if (nt < 8) {
      int col = nt * 16 + cb;
      float4 bb = *(const float4*)(b1 + col);
      v[0] = fmaxf(v[0] + bb.x, 0.f); v[1] = fmaxf(v[1] + bb.y, 0.f);
      v[2] = fmaxf(v[2] + bb.z, 0.f); v[3] = fmaxf(v[3] + bb.w, 0.f);
      *(us4*)(h1out + (size_t)row * 256 + col) = pack4(v);
    } else if (nt < 16) {
      int col = (nt - 8) * 16 + cb;
      float4 bb = *(const float4*)(br1 + col);
      v[0] += bb.x; v[1] += bb.y; v[2] += bb.z; v[3] += bb.w;
      *(us4*)(res1 + (size_t)row * 128 + col) = pack4(v);
    } else {
      int col = (nt - 16) * 16 + cb;
      float4 bb = *(const float4*)(br2 + col);
      v[0] += bb.x; v[1] += bb.y; v[2] += bb.z; v[3] += bb.w;
      *(us4*)(res2 + (size_t)row * 64 + col) = pack4(v);
    }
  }
}

// ---------------- GEMM2/3: A[NN x 256] @ Bp -> out (+bias, +res(bf16), relu/sig8) -
// grid (NTT/4, 782): x = tile-group, y = row block. 4-tile B-panel (32 KB) in LDS.
template <int NTT>
__global__ __launch_bounds__(256) void gemm23_kernel(
    const unsigned short* __restrict__ A,
    const unsigned short* __restrict__ Bp,
    const float* __restrict__ bias,
    const unsigned short* __restrict__ res, int res_stride,
    unsigned short* __restrict__ out_bf,   // stride 256, may be null
    float* __restrict__ out_f, int of_stride,
    int relu, int sig8)
{
  const int TILES = 4;
  __shared__ unsigned short Bs[TILES * 8 * 512];   // 32 KB
  int tid = threadIdx.x;
  int wave = tid >> 6, lane = tid & 63;
  int ybase = blockIdx.x * TILES;
#pragma unroll
  for (int i = tid; i < TILES * 64 * 8; i += 256) {
    int k0i = i / (TILES * 64), r = i % (TILES * 64);
    *(us8*)(Bs + (size_t)k0i * TILES * 512 + (size_t)r * 8) =
        *(const us8*)(Bp + ((size_t)k0i * NTT + ybase) * 512 + (size_t)r * 8);
  }
  int row0 = blockIdx.y * 64 + wave * 16;
  int m = lane & 15, q = lane >> 4;
  const unsigned short* arow = A + (size_t)(row0 + m) * 256 + q * 8;
  bf16x8 af[8];
#pragma unroll
  for (int k0i = 0; k0i < 8; ++k0i) af[k0i] = *(const bf16x8*)(arow + k0i * 32);
  __syncthreads();
  f32x4 acc[TILES];
#pragma unroll
  for (int i = 0; i < TILES; i++) acc[i] = (f32x4){0.f, 0.f, 0.f, 0.f};
#pragma unroll
  for (int k0i = 0; k0i < 8; ++k0i) {
    const unsigned short* bk = Bs + (size_t)k0i * TILES * 512 + lane * 8;
#pragma unroll
    for (int s = 0; s < TILES; ++s) {
      bf16x8 bfr = *(const bf16x8*)(bk + s * 512);
      acc[s] = __builtin_amdgcn_mfma_f32_16x16x32_bf16(bfr, af[k0i], acc[s], 0, 0, 0);
    }
  }
  int row = row0 + m;
  if (row >= NN) return;
  int cb = q * 4;
#pragma unroll
  for (int s = 0; s < TILES; ++s) {
    int col = (ybase + s) * 16 + cb;
    f32x4 v = acc[s];
    float4 bb = *(const float4*)(bias + col);
    v[0] += bb.x; v[1] += bb.y; v[2] += bb.z; v[3] += bb.w;
    if (relu) {
#pragma unroll
      for (int r = 0; r < 4; r++) v[r] = fmaxf(v[r], 0.f);
    }
    if (res) {
      us4 rv = *(const us4*)(res + (size_t)row * res_stride + col);
#pragma unroll
      for (int r = 0; r < 4; r++) v[r] += bf2f(rv[r]);
    }
    if (sig8 && col < 8) {
#pragma unroll
      for (int r = 0; r < 4; r++) v[r] = 1.f / (1.f + __expf(-v[r]));
    }
    if (out_bf) *(us4*)(out_bf + (size_t)row * 256 + col) = pack4(v);
    if (out_f) {
      float4 o = { v[0], v[1], v[2], v[3] };
      *(float4*)(out_f + (size_t)row * of_stride + col) = o;
    }
  }
}

extern "C" void kernel_launch(void* const* d_in, const int* in_sizes, int n_in,
                              void* d_out, int out_size, void* d_ws, size_t ws_size,
                              hipStream_t stream) {
  const float* z   = (const float*)d_in[0];
  const int*   edge = (const int*)d_in[1];
  const int*   srcn = edge;        // edge_index[0]
  const int*   dstn = edge + NE;   // edge_index[1]
  const float* w1n = (const float*)d_in[2];
  const float* w1r = (const float*)d_in[3];
  const float* b1  = (const float*)d_in[4];
  const float* w2n = (const float*)d_in[5];
  const float* w2r = (const float*)d_in[6];
  const float* b2  = (const float*)d_in[7];
  const float* wfn = (const float*)d_in[8];
  const float* wfr = (const float*)d_in[9];
  const float* bfb = (const float*)d_in[10];
  const float* wr1 = (const float*)d_in[11];
  const float* br1 = (const float*)d_in[12];
  const float* wr2 = (const float*)d_in[13];
  const float* br2 = (const float*)d_in[14];
  float* out = (float*)d_out;

  char* p = (char*)d_ws;
  auto alloc = [&](size_t bytes) { char* r = p; p += (bytes + 255) & ~255ull; return r; };
  int* rowoff = (int*)alloc((size_t)(NN + 1) * 4);
  int* bhist  = (int*)alloc((size_t)NB * 4);
  int* bucket_off = (int*)alloc((size_t)(NB + 1) * 4);
  int* gcur   = (int*)alloc((size_t)NB * 4);
  int* csr    = (int*)alloc((size_t)NE * 4);
  unsigned short* A1 = (unsigned short*)alloc((size_t)NN * 256 * 2);  // [mean1|z_bf], later reused as A3
  unsigned short* A2 = (unsigned short*)alloc((size_t)NN * 256 * 2);  // [mean2|h1]
  unsigned short* res1 = (unsigned short*)alloc((size_t)NN * 128 * 2);
  unsigned short* res2 = (unsigned short*)alloc((size_t)NN * 64 * 2);
  unsigned short* Bp1 = (unsigned short*)alloc(10240 * 8 * 2);
  unsigned short* Bp2 = (unsigned short*)alloc(4096 * 8 * 2);
  unsigned short* Bp3 = (unsigned short*)alloc(2048 * 8 * 2);
  unsigned short* A3 = A1;  // alias: A1 dead once gemm1 outputs land
  // ebuf aliases res1 (6.4 MB <= 12.8 MB): dead before gemm1 writes res1
  unsigned long long* ebuf = (unsigned long long*)res1;

  // CSR build (bucketed counting sort; only bhist needs pre-zero)
  hipMemsetAsync(bhist, 0, (size_t)NB * 4, stream);
  bhist_kernel<<<128, 256, 0, stream>>>(dstn, bhist);
  bscan_kernel<<<1, 512, 0, stream>>>(bhist, bucket_off, gcur);
  bscat_kernel<<<128, 256, 0, stream>>>(srcn, dstn, bucket_off, gcur, ebuf);
  bfill_kernel<<<NB, 256, 0, stream>>>(ebuf, bucket_off, rowoff, csr);

  // weight prep + z conversion
  prep_kernel<<<64, 256, 0, stream>>>(w1n, w1r, w2n, w2r, wfn, wfr, wr1, wr2, Bp1, Bp2, Bp3);
  convz_kernel<<<(NN * 128 / 4 + 255) / 256, 256, 0, stream>>>(z, A1);

  const int gy = (NN + 63) / 64;      // 782 row-blocks
  const int agg_blocks = (NN + 3) / 4;  // 12500

  // layer 1: mean1 = agg(z); fused GEMM -> h1 (A2 right), res1, res2 (bf16)
  agg_kernel<<<agg_blocks, 256, 0, stream>>>(A1 + 128, 256, A1, 256, rowoff, csr);
  gemm1_kernel<<<dim3(4, gy), 256, 0, stream>>>(A1, Bp1, b1, br1, br2, A2 + 128, res1, res2);

  // layer 2: mean2 = agg(h1); h2 = relu([mean2|h1]@W2+b2) + res1 -> A3 right
  agg_kernel<<<agg_blocks, 256, 0, stream>>>(A2 + 128, 256, A2, 256, rowoff, csr);
  gemm23_kernel<8><<<dim3(2, gy), 256, 0, stream>>>(A2, Bp2, b2, res1, 128,
      A3 + 128, nullptr, 0, 1, 0);

  // layer 3: mean3 = agg(h2); out = [mean3|h2]@Wf+bf + res2, sigmoid cols 0..7
  agg_kernel<<<agg_blocks, 256, 0, stream>>>(A3 + 128, 256, A3, 256, rowoff, csr);
  gemm23_kernel<4><<<dim3(1, gy), 256, 0, stream>>>(A3, Bp3, bfb, res2, 64,
      nullptr, out, 64, 0, 1);
}

// Round 8
// 294.711 us; speedup vs baseline: 1.9553x; 1.0098x over previous
//
#include <hip/hip_runtime.h>
#include <hip/hip_bf16.h>
#include <math.h>

#define NN 50000
#define NE 800000
#define NB 391          // buckets of 128 nodes: ceil(50000/128)
#define EPB 6250        // edges per bscat/bhist block (128 blocks)

typedef short bf16x8 __attribute__((ext_vector_type(8)));
typedef float f32x4 __attribute__((ext_vector_type(4)));
typedef unsigned short us4 __attribute__((ext_vector_type(4)));
typedef unsigned short us8 __attribute__((ext_vector_type(8)));
typedef unsigned int u32x4 __attribute__((ext_vector_type(4)));

__device__ __forceinline__ float bf2f(unsigned short u) {
  union { unsigned int i; float f; } x; x.i = ((unsigned int)u) << 16; return x.f;
}
__device__ __forceinline__ unsigned short f2bf(float f) {
  union { float f; unsigned int i; } x; x.f = f;
  unsigned int i = x.i;
  unsigned int r = i + 0x7FFF + ((i >> 16) & 1);   // round-to-nearest-even
  return (unsigned short)(r >> 16);
}
__device__ __forceinline__ us4 pack4(f32x4 v) {
  us4 o; o[0] = f2bf(v[0]); o[1] = f2bf(v[1]); o[2] = f2bf(v[2]); o[3] = f2bf(v[3]);
  return o;
}

// ---------------- CSR build, bucketed (all random scatter kept in LDS) --------
__global__ __launch_bounds__(512) void bscan_kernel(const int* __restrict__ bhist,
                                                    int* __restrict__ bucket_off,
                                                    int* __restrict__ gcur) {
  __shared__ int s[512];
  int t = threadIdx.x;
  int v = (t < NB) ? bhist[t] : 0;
  s[t] = v; __syncthreads();
  for (int off = 1; off < 512; off <<= 1) {
    int x = (t >= off) ? s[t - off] : 0;
    __syncthreads();
    s[t] += x;
    __syncthreads();
  }
  if (t < NB) { bucket_off[t] = s[t] - v; gcur[t] = 0; }
  if (t == NB - 1) bucket_off[NB] = s[t];
}

__global__ __launch_bounds__(256) void bscat_kernel(const int* __restrict__ srcn,
                                                    const int* __restrict__ dstn,
                                                    const int* __restrict__ bucket_off,
                                                    int* __restrict__ gcur,
                                                    unsigned long long* __restrict__ ebuf) {
  __shared__ int hist[NB];
  __shared__ int base[NB];
  for (int i = threadIdx.x; i < NB; i += 256) hist[i] = 0;
  __syncthreads();
  int e0 = blockIdx.x * EPB;
  for (int i = threadIdx.x; i < EPB; i += 256)
    atomicAdd(&hist[dstn[e0 + i] >> 7], 1);
  __syncthreads();
  for (int i = threadIdx.x; i < NB; i += 256) {
    int c = hist[i];
    base[i] = c ? (bucket_off[i] + atomicAdd(&gcur[i], c)) : 0;
  }
  __syncthreads();
  for (int i = threadIdx.x; i < EPB; i += 256) {
    int s = srcn[e0 + i], d = dstn[e0 + i];
    int b = d >> 7;
    int pos = atomicSub(&hist[b], 1) - 1;   // order within slice irrelevant
    ebuf[(size_t)base[b] + pos] = ((unsigned long long)(unsigned)d << 32) | (unsigned)s;
  }
}

__global__ __launch_bounds__(256) void bfill_kernel(const unsigned long long* __restrict__ ebuf,
                                                    const int* __restrict__ bucket_off,
                                                    int* __restrict__ rowoff,
                                                    int* __restrict__ csr) {
  int b = blockIdx.x;
  int bo = bucket_off[b], cnt = bucket_off[b + 1] - bo;
  __shared__ int ndeg[128], noff[128];
  int t = threadIdx.x;
  if (t < 128) ndeg[t] = 0;
  __syncthreads();
  for (int i = t; i < cnt; i += 256)
    atomicAdd(&ndeg[(int)(ebuf[bo + i] >> 32) & 127], 1);
  __syncthreads();
  if (t < 128) noff[t] = ndeg[t];
  __syncthreads();
  for (int off = 1; off < 128; off <<= 1) {   // inclusive scan (Hillis-Steele)
    int x = 0;
    if (t < 128 && t >= off) x = noff[t - off];
    __syncthreads();
    if (t < 128 && t >= off) noff[t] += x;
    __syncthreads();
  }
  if (t < 128) {
    int ex = noff[t] - ndeg[t];    // exclusive
    noff[t] = ex;
    int node = b * 128 + t;
    if (node < NN) rowoff[node] = bo + ex;
  }
  if (b == NB - 1 && t == 0) rowoff[NN] = NE;
  __syncthreads();
  for (int i = t; i < cnt; i += 256) {
    unsigned long long e = ebuf[bo + i];
    int dl = (int)(e >> 32) & 127;
    int pos = atomicSub(&ndeg[dl], 1) - 1;
    csr[bo + noff[dl] + pos] = (int)(unsigned)e;
  }
}

// ---------------- fused setup: convz (6250 blocks) | prep (64) | bhist (128) ----
// prep packs B into MFMA fragment-major layout:
//   frag fi = (k0i*NT + nt)*64 + lane; lane (m=lane&15,q=lane>>4) holds
//   W[k][n], k = k0i*32+q*8+j, n = nt*16+m.
// Bp1 = [w1n;w1r | 0;wr1 | 0;wr2] (NT=20).  Bp2 = [w2n;w2r] (NT=8).  Bp3 = [wfn;wfr] (NT=4).
__global__ __launch_bounds__(256) void setup_kernel(
    const float* __restrict__ z, unsigned short* __restrict__ A1,
    const float* __restrict__ w1n, const float* __restrict__ w1r,
    const float* __restrict__ w2n, const float* __restrict__ w2r,
    const float* __restrict__ wfn, const float* __restrict__ wfr,
    const float* __restrict__ wr1, const float* __restrict__ wr2,
    unsigned short* __restrict__ Bp1, unsigned short* __restrict__ Bp2,
    unsigned short* __restrict__ Bp3,
    const int* __restrict__ dstn, int* __restrict__ bhist) {
  __shared__ int h[NB];
  int b = blockIdx.x;
  if (b < 6250) {               // ---- convz: z (f32) -> bf16 into A1 right half
    int i = b * 256 + threadIdx.x;   // groups of 4 elements
    if (i >= NN * 128 / 4) return;
    int i4 = i * 4;
    int row = i4 >> 7, c = i4 & 127;
    float4 v = *(const float4*)(z + i4);
    us4 o = { f2bf(v.x), f2bf(v.y), f2bf(v.z), f2bf(v.w) };
    *(us4*)(A1 + (size_t)row * 256 + 128 + c) = o;
  } else if (b < 6314) {        // ---- prep
    int g = (b - 6250) * 256 + threadIdx.x;
    unsigned short* D; int NT, fi;
    int which;  // 1,2,3
    if      (g < 10240) { fi = g;         D = Bp1; NT = 20; which = 1; }
    else if (g < 14336) { fi = g - 10240; D = Bp2; NT = 8;  which = 2; }
    else if (g < 16384) { fi = g - 14336; D = Bp3; NT = 4;  which = 3; }
    else return;
    int lane = fi & 63, t = fi >> 6;
    int nt = t % NT, k0i = t / NT;
    int m = lane & 15, q = lane >> 4;
    int kb = k0i * 32 + q * 8;          // 8-aligned: all j on same side of 128
    int n = nt * 16 + m;
    int hi = (kb >= 128);
    int k0_ = kb - (hi ? 128 : 0);
    const float* W = nullptr; int Nseg = 128; int nn = n;
    if (which == 1) {
      if (n < 128)      { W = hi ? w1r : w1n; nn = n; Nseg = 128; }
      else if (n < 256) { W = hi ? wr1 : nullptr; nn = n - 128; Nseg = 128; }
      else              { W = hi ? wr2 : nullptr; nn = n - 256; Nseg = 64; }
    } else if (which == 2) { W = hi ? w2r : w2n; Nseg = 128; }
    else                   { W = hi ? wfr : wfn; Nseg = 64; }
    unsigned short o[8];
#pragma unroll
    for (int j = 0; j < 8; j++)
      o[j] = W ? f2bf(W[(size_t)(k0_ + j) * Nseg + nn]) : (unsigned short)0;
    *(us8*)(D + (size_t)fi * 8) = *(const us8*)o;
  } else {                      // ---- bhist
    for (int i = threadIdx.x; i < NB; i += 256) h[i] = 0;
    __syncthreads();
    int e0 = (b - 6314) * EPB;
    for (int i = threadIdx.x; i < EPB; i += 256)
      atomicAdd(&h[dstn[e0 + i] >> 7], 1);
    __syncthreads();
    for (int i = threadIdx.x; i < NB; i += 256)
      if (h[i]) atomicAdd(&bhist[i], h[i]);
  }
}

// ---------------- mean aggregation: one wave per node, branchless 4-deep tail ---
// 4 subgroups of 16 lanes; each handles neighbors g, g+4, g+8, ... with 16B/lane
// loads. Every iteration issues 4 row-reads (tail indices clamped to end-1 with
// 0/1 fma weights) so 4 loads stay in flight even for partial tails.
__global__ __launch_bounds__(256) void agg_kernel(const unsigned short* __restrict__ feat, int fstride,
                                                  unsigned short* __restrict__ outm, int ostride,
                                                  const int* __restrict__ rowoff,
                                                  const int* __restrict__ csr) {
  int wave = threadIdx.x >> 6, lane = threadIdx.x & 63;
  int node = blockIdx.x * 4 + wave;
  if (node >= NN) return;
  int beg = rowoff[node], end = rowoff[node + 1];
  int g = lane >> 4;           // neighbor subgroup 0..3
  int c = (lane & 15) << 3;    // column offset (8 bf16 = 16B per lane)
  float a[8];
#pragma unroll
  for (int i = 0; i < 8; i++) a[i] = 0.f;
  int e1 = end - 1;
  for (int j = beg + g; j < end; j += 16) {
    int j1 = (j + 4 < e1) ? j + 4 : e1;
    int j2 = (j + 8 < e1) ? j + 8 : e1;
    int j3 = (j + 12 < e1) ? j + 12 : e1;
    int s0 = csr[j], s1 = csr[j1], s2 = csr[j2], s3 = csr[j3];
    float w1 = (j + 4 < end) ? 1.f : 0.f;
    float w2 = (j + 8 < end) ? 1.f : 0.f;
    float w3 = (j + 12 < end) ? 1.f : 0.f;
    u32x4 v0 = *(const u32x4*)(feat + (size_t)s0 * fstride + c);
    u32x4 v1 = *(const u32x4*)(feat + (size_t)s1 * fstride + c);
    u32x4 v2 = *(const u32x4*)(feat + (size_t)s2 * fstride + c);
    u32x4 v3 = *(const u32x4*)(feat + (size_t)s3 * fstride + c);
#pragma unroll
    for (int i = 0; i < 4; i++) {
      float l0 = bf2f((unsigned short)(v0[i] & 0xffff));
      float h0 = bf2f((unsigned short)(v0[i] >> 16));
      l0 = fmaf(w1, bf2f((unsigned short)(v1[i] & 0xffff)), l0);
      h0 = fmaf(w1, bf2f((unsigned short)(v1[i] >> 16)), h0);
      l0 = fmaf(w2, bf2f((unsigned short)(v2[i] & 0xffff)), l0);
      h0 = fmaf(w2, bf2f((unsigned short)(v2[i] >> 16)), h0);
      l0 = fmaf(w3, bf2f((unsigned short)(v3[i] & 0xffff)), l0);
      h0 = fmaf(w3, bf2f((unsigned short)(v3[i] >> 16)), h0);
      a[2*i] += l0;
      a[2*i+1] += h0;
    }
  }
#pragma unroll
  for (int i = 0; i < 8; i++) {
    a[i] += __shfl_xor(a[i], 16, 64);
    a[i] += __shfl_xor(a[i], 32, 64);
  }
  if (g == 0) {
    float inv = 1.f / fmaxf((float)(end - beg), 1.f);
    unsigned int o[4];
#pragma unroll
    for (int i = 0; i < 4; i++)
      o[i] = ((unsigned int)f2bf(a[2*i+1] * inv) << 16) | f2bf(a[2*i] * inv);
    *(u32x4*)(outm + (size_t)node * ostride + c) = *(const u32x4*)o;
  }
}

// ---------------- GEMM1: A1[NN x 256] @ Bp1(NT=20) -> h1 | res1 | res2 ----------
// grid (4, 391): x = tile-group (fastest -> consecutive blocks share A via L2),
// y = 128-row block (32 rows/wave: 2 A-sets per B-fragment -> 2x MFMA/ds_read).
// 5-tile B-panel (40 KB) staged in LDS once.
__global__ __launch_bounds__(256) void gemm1_kernel(
    const unsigned short* __restrict__ A,
    const unsigned short* __restrict__ Bp,
    const float* __restrict__ b1, const float* __restrict__ br1, const float* __restrict__ br2,
    unsigned short* __restrict__ h1out,   // A2+128, stride 256
    unsigned short* __restrict__ res1, unsigned short* __restrict__ res2)
{
  const int NT = 20, TILES = 5;
  __shared__ unsigned short Bs[TILES * 8 * 512];   // 40 KB
  int tid = threadIdx.x;
  int wave = tid >> 6, lane = tid & 63;
  int ybase = blockIdx.x * TILES;
  int row0 = blockIdx.y * 128 + wave * 16;
  int m = lane & 15, q = lane >> 4;
  const unsigned short* arow0 = A + (size_t)(row0 + m) * 256 + q * 8;
  const unsigned short* arow1 = arow0 + 64 * 256;
  bf16x8 af0[8], af1[8];
#pragma unroll
  for (int k0i = 0; k0i < 8; ++k0i) {
    af0[k0i] = *(const bf16x8*)(arow0 + k0i * 32);
    af1[k0i] = *(const bf16x8*)(arow1 + k0i * 32);
  }
#pragma unroll
  for (int i = tid; i < TILES * 64 * 8; i += 256) {     // us8 copies
    int k0i = i / (TILES * 64), r = i % (TILES * 64);
    *(us8*)(Bs + (size_t)k0i * TILES * 512 + (size_t)r * 8) =
        *(const us8*)(Bp + ((size_t)k0i * NT + ybase) * 512 + (size_t)r * 8);
  }
  __syncthreads();
  f32x4 acc[2][TILES];
#pragma unroll
  for (int h = 0; h < 2; h++)
#pragma unroll
    for (int i = 0; i < TILES; i++) acc[h][i] = (f32x4){0.f, 0.f, 0.f, 0.f};
#pragma unroll
  for (int k0i = 0; k0i < 8; ++k0i) {
    const unsigned short* bk = Bs + (size_t)k0i * TILES * 512 + lane * 8;
#pragma unroll
    for (int s = 0; s < TILES; ++s) {
      bf16x8 bfr = *(const bf16x8*)(bk + s * 512);
      acc[0][s] = __builtin_amdgcn_mfma_f32_16x16x32_bf16(bfr, af0[k0i], acc[0][s], 0, 0, 0);
      acc[1][s] = __builtin_amdgcn_mfma_f32_16x16x32_bf16(bfr, af1[k0i], acc[1][s], 0, 0, 0);
    }
  }
  int cb = q * 4;
#pragma unroll
  for (int h = 0; h < 2; h++) {
    int row = row0 + h * 64 + m;
    if (row >= NN) continue;
#pragma unroll
    for (int s = 0; s < TILES; ++s) {
      int nt = ybase + s;
      f32x4 v = acc[h][s];
      if (nt < 8) {
        int col = nt * 16 + cb;
        float4 bb = *(const float4*)(b1 + col);
        v[0] = fmaxf(v[0] + bb.x, 0.f); v[1] = fmaxf(v[1] + bb.y, 0.f);
        v[2] = fmaxf(v[2] + bb.z, 0.f); v[3] = fmaxf(v[3] + bb.w, 0.f);
        *(us4*)(h1out + (size_t)row * 256 + col) = pack4(v);
      } else if (nt < 16) {
        int col = (nt - 8) * 16 + cb;
        float4 bb = *(const float4*)(br1 + col);
        v[0] += bb.x; v[1] += bb.y; v[2] += bb.z; v[3] += bb.w;
        *(us4*)(res1 + (size_t)row * 128 + col) = pack4(v);
      } else {
        int col = (nt - 16) * 16 + cb;
        float4 bb = *(const float4*)(br2 + col);
        v[0] += bb.x; v[1] += bb.y; v[2] += bb.z; v[3] += bb.w;
        *(us4*)(res2 + (size_t)row * 64 + col) = pack4(v);
      }
    }
  }
}

// ---------------- GEMM2/3: A[NN x 256] @ Bp -> out (+bias, +res(bf16), relu/sig8) -
// RPW = row-sets per wave (32 or 16 rows). grid (NTT/4, y-blocks). 32 KB B-panel.
template <int NTT, int RPW>
__global__ __launch_bounds__(256) void gemm23_kernel(
    const unsigned short* __restrict__ A,
    const unsigned short* __restrict__ Bp,
    const float* __restrict__ bias,
    const unsigned short* __restrict__ res, int res_stride,
    unsigned short* __restrict__ out_bf,   // stride 256, may be null
    float* __restrict__ out_f, int of_stride,
    int relu, int sig8)
{
  const int TILES = 4;
  __shared__ unsigned short Bs[TILES * 8 * 512];   // 32 KB
  int tid = threadIdx.x;
  int wave = tid >> 6, lane = tid & 63;
  int ybase = blockIdx.x * TILES;
  int row0 = blockIdx.y * (64 * RPW) + wave * 16;
  int m = lane & 15, q = lane >> 4;
  bf16x8 af[RPW][8];
#pragma unroll
  for (int h = 0; h < RPW; h++) {
    const unsigned short* arow = A + (size_t)(row0 + h * 64 + m) * 256 + q * 8;
#pragma unroll
    for (int k0i = 0; k0i < 8; ++k0i) af[h][k0i] = *(const bf16x8*)(arow + k0i * 32);
  }
#pragma unroll
  for (int i = tid; i < TILES * 64 * 8; i += 256) {
    int k0i = i / (TILES * 64), r = i % (TILES * 64);
    *(us8*)(Bs + (size_t)k0i * TILES * 512 + (size_t)r * 8) =
        *(const us8*)(Bp + ((size_t)k0i * NTT + ybase) * 512 + (size_t)r * 8);
  }
  __syncthreads();
  f32x4 acc[RPW][TILES];
#pragma unroll
  for (int h = 0; h < RPW; h++)
#pragma unroll
    for (int i = 0; i < TILES; i++) acc[h][i] = (f32x4){0.f, 0.f, 0.f, 0.f};
#pragma unroll
  for (int k0i = 0; k0i < 8; ++k0i) {
    const unsigned short* bk = Bs + (size_t)k0i * TILES * 512 + lane * 8;
#pragma unroll
    for (int s = 0; s < TILES; ++s) {
      bf16x8 bfr = *(const bf16x8*)(bk + s * 512);
#pragma unroll
      for (int h = 0; h < RPW; h++)
        acc[h][s] = __builtin_amdgcn_mfma_f32_16x16x32_bf16(bfr, af[h][k0i], acc[h][s], 0, 0, 0);
    }
  }
  int cb = q * 4;
#pragma unroll
  for (int h = 0; h < RPW; h++) {
    int row = row0 + h * 64 + m;
    if (row >= NN) continue;
#pragma unroll
    for (int s = 0; s < TILES; ++s) {
      int col = (ybase + s) * 16 + cb;
      f32x4 v = acc[h][s];
      float4 bb = *(const float4*)(bias + col);
      v[0] += bb.x; v[1] += bb.y; v[2] += bb.z; v[3] += bb.w;
      if (relu) {
#pragma unroll
        for (int r = 0; r < 4; r++) v[r] = fmaxf(v[r], 0.f);
      }
      if (res) {
        us4 rv = *(const us4*)(res + (size_t)row * res_stride + col);
#pragma unroll
        for (int r = 0; r < 4; r++) v[r] += bf2f(rv[r]);
      }
      if (sig8 && col < 8) {
#pragma unroll
        for (int r = 0; r < 4; r++) v[r] = 1.f / (1.f + __expf(-v[r]));
      }
      if (out_bf) *(us4*)(out_bf + (size_t)row * 256 + col) = pack4(v);
      if (out_f) {
        float4 o = { v[0], v[1], v[2], v[3] };
        *(float4*)(out_f + (size_t)row * of_stride + col) = o;
      }
    }
  }
}

extern "C" void kernel_launch(void* const* d_in, const int* in_sizes, int n_in,
                              void* d_out, int out_size, void* d_ws, size_t ws_size,
                              hipStream_t stream) {
  const float* z   = (const float*)d_in[0];
  const int*   edge = (const int*)d_in[1];
  const int*   srcn = edge;        // edge_index[0]
  const int*   dstn = edge + NE;   // edge_index[1]
  const float* w1n = (const float*)d_in[2];
  const float* w1r = (const float*)d_in[3];
  const float* b1  = (const float*)d_in[4];
  const float* w2n = (const float*)d_in[5];
  const float* w2r = (const float*)d_in[6];
  const float* b2  = (const float*)d_in[7];
  const float* wfn = (const float*)d_in[8];
  const float* wfr = (const float*)d_in[9];
  const float* bfb = (const float*)d_in[10];
  const float* wr1 = (const float*)d_in[11];
  const float* br1 = (const float*)d_in[12];
  const float* wr2 = (const float*)d_in[13];
  const float* br2 = (const float*)d_in[14];
  float* out = (float*)d_out;

  char* p = (char*)d_ws;
  auto alloc = [&](size_t bytes) { char* r = p; p += (bytes + 255) & ~255ull; return r; };
  int* rowoff = (int*)alloc((size_t)(NN + 1) * 4);
  int* bhist  = (int*)alloc((size_t)NB * 4);
  int* bucket_off = (int*)alloc((size_t)(NB + 1) * 4);
  int* gcur   = (int*)alloc((size_t)NB * 4);
  int* csr    = (int*)alloc((size_t)NE * 4);
  unsigned short* A1 = (unsigned short*)alloc((size_t)NN * 256 * 2);  // [mean1|z_bf], later reused as A3
  unsigned short* A2 = (unsigned short*)alloc((size_t)NN * 256 * 2);  // [mean2|h1]
  unsigned short* res1 = (unsigned short*)alloc((size_t)NN * 128 * 2);
  unsigned short* res2 = (unsigned short*)alloc((size_t)NN * 64 * 2);
  unsigned short* Bp1 = (unsigned short*)alloc(10240 * 8 * 2);
  unsigned short* Bp2 = (unsigned short*)alloc(4096 * 8 * 2);
  unsigned short* Bp3 = (unsigned short*)alloc(2048 * 8 * 2);
  unsigned short* A3 = A1;  // alias: A1 dead once gemm1 outputs land
  // ebuf aliases res1 (6.4 MB <= 12.8 MB): dead before gemm1 writes res1
  unsigned long long* ebuf = (unsigned long long*)res1;

  hipMemsetAsync(bhist, 0, (size_t)NB * 4, stream);
  // fused prologue: convz | prep | bhist
  setup_kernel<<<6442, 256, 0, stream>>>(z, A1, w1n, w1r, w2n, w2r, wfn, wfr, wr1, wr2,
                                         Bp1, Bp2, Bp3, dstn, bhist);
  bscan_kernel<<<1, 512, 0, stream>>>(bhist, bucket_off, gcur);
  bscat_kernel<<<128, 256, 0, stream>>>(srcn, dstn, bucket_off, gcur, ebuf);
  bfill_kernel<<<NB, 256, 0, stream>>>(ebuf, bucket_off, rowoff, csr);

  const int gy128 = (NN + 127) / 128;   // 391
  const int gy64  = (NN + 63) / 64;     // 782
  const int agg_blocks = (NN + 3) / 4;  // 12500

  // layer 1: mean1 = agg(z); fused GEMM -> h1 (A2 right), res1, res2 (bf16)
  agg_kernel<<<agg_blocks, 256, 0, stream>>>(A1 + 128, 256, A1, 256, rowoff, csr);
  gemm1_kernel<<<dim3(4, gy128), 256, 0, stream>>>(A1, Bp1, b1, br1, br2, A2 + 128, res1, res2);

  // layer 2: mean2 = agg(h1); h2 = relu([mean2|h1]@W2+b2) + res1 -> A3 right
  agg_kernel<<<agg_blocks, 256, 0, stream>>>(A2 + 128, 256, A2, 256, rowoff, csr);
  gemm23_kernel<8, 2><<<dim3(2, gy128), 256, 0, stream>>>(A2, Bp2, b2, res1, 128,
      A3 + 128, nullptr, 0, 1, 0);

  // layer 3: mean3 = agg(h2); out = [mean3|h2]@Wf+bf + res2, sigmoid cols 0..7
  agg_kernel<<<agg_blocks, 256, 0, stream>>>(A3 + 128, 256, A3, 256, rowoff, csr);
  gemm23_kernel<4, 1><<<dim3(1, gy64), 256, 0, stream>>>(A3, Bp3, bfb, res2, 64,
      nullptr, out, 64, 0, 1);
}